// Round 3
// baseline (213.816 us; speedup 1.0000x reference)
//
#include <hip/hip_runtime.h>
#include <hip/hip_bf16.h>

// Problem constants: B=2, N=2048, C=1024, H=16, D=64  (head_dim)
// M = B*N = 4096 rows. qkv layout along 3C axis: three*1024 + h*64 + d.

typedef __bf16 bf16x8 __attribute__((ext_vector_type(8)));
typedef float f32x4 __attribute__((ext_vector_type(4)));
typedef unsigned short us8 __attribute__((ext_vector_type(8)));
typedef unsigned short us4 __attribute__((ext_vector_type(4)));

static __device__ __forceinline__ unsigned short f2b(float f) {
  __hip_bfloat16 h = __float2bfloat16(f);
  return __builtin_bit_cast(unsigned short, h);
}
static __device__ __forceinline__ float b2f(unsigned short u) {
  __hip_bfloat16 h = __builtin_bit_cast(__hip_bfloat16, u);
  return __bfloat162float(h);
}

// async global->LDS, 16B per lane. LDS dest = wave-uniform base + lane*16.
static __device__ __forceinline__ void async_copy16(void* lds, const void* g) {
  __builtin_amdgcn_global_load_lds(
      (const __attribute__((address_space(1))) void*)g,
      (__attribute__((address_space(3))) void*)lds, 16, 0, 0);
}

// ---------------------------------------------------------------- convert
__global__ __launch_bounds__(256) void cvt_bf16(
    const float* __restrict__ in, unsigned short* __restrict__ out, int n8) {
  int i = blockIdx.x * 256 + threadIdx.x;
  if (i >= n8) return;
  const float4* p = reinterpret_cast<const float4*>(in) + (size_t)i * 2;
  float4 a = p[0], b = p[1];
  us8 v;
  v[0] = f2b(a.x); v[1] = f2b(a.y); v[2] = f2b(a.z); v[3] = f2b(a.w);
  v[4] = f2b(b.x); v[5] = f2b(b.y); v[6] = f2b(b.z); v[7] = f2b(b.w);
  reinterpret_cast<us8*>(out)[i] = v;
}

// ---------------------------------------------------------------- GEMM (B^T)
// C[m][n] = sum_k A[m][k] * Bw[n][k]. 128x128 tile, BK=32, 4 waves (2x2).
// Staging via global_load_lds w/ source-side XOR swizzle (LDS stays linear).
template <int MODE>
__global__ __launch_bounds__(256) void gemm_bt(
    const unsigned short* __restrict__ A, const unsigned short* __restrict__ Bw,
    const float* __restrict__ bias, void* __restrict__ Cout,
    int M, int Nn, int K) {
  __shared__ unsigned short a_sh[128 * 32];
  __shared__ unsigned short b_sh[128 * 32];
  const int tid = threadIdx.x;
  const int lane = tid & 63;
  const int w = tid >> 6;
  const int wr = w >> 1, wc = w & 1;
  const int l15 = lane & 15, l4 = lane >> 4;
  const int m0 = blockIdx.y * 128;
  const int n0 = blockIdx.x * 128;

  f32x4 acc[4][4] = {};

  for (int k0 = 0; k0 < K; k0 += 32) {
    // stage: 16 segments of 16 rows x 32 shorts (1KB); 4 per wave
#pragma unroll
    for (int p = 0; p < 4; ++p) {
      int s = p * 4 + w;
      int row = ((s & 7) << 4) + (lane >> 2);
      int c = lane & 3;
      int sw = (c ^ ((row >> 1) & 3)) << 3;  // source-side swizzle (involution)
      if (s < 8)
        async_copy16(&a_sh[s * 512], &A[(size_t)(m0 + row) * K + k0 + sw]);
      else
        async_copy16(&b_sh[(s - 8) * 512], &Bw[(size_t)(n0 + row) * K + k0 + sw]);
    }
    __syncthreads();  // drains vmcnt (global_load_lds) per barrier semantics
    bf16x8 af[4], bfr[4];
#pragma unroll
    for (int mf = 0; mf < 4; ++mf) {
      int r = wr * 64 + mf * 16 + l15;
      af[mf] = *reinterpret_cast<const bf16x8*>(&a_sh[r * 32 + ((l4 ^ ((r >> 1) & 3)) << 3)]);
    }
#pragma unroll
    for (int nf = 0; nf < 4; ++nf) {
      int r = wc * 64 + nf * 16 + l15;
      bfr[nf] = *reinterpret_cast<const bf16x8*>(&b_sh[r * 32 + ((l4 ^ ((r >> 1) & 3)) << 3)]);
    }
#pragma unroll
    for (int mf = 0; mf < 4; ++mf)
#pragma unroll
      for (int nf = 0; nf < 4; ++nf)
        acc[mf][nf] = __builtin_amdgcn_mfma_f32_16x16x32_bf16(af[mf], bfr[nf], acc[mf][nf], 0, 0, 0);
    __syncthreads();
  }
#pragma unroll
  for (int mf = 0; mf < 4; ++mf)
#pragma unroll
    for (int nf = 0; nf < 4; ++nf) {
      int col = n0 + wc * 64 + nf * 16 + l15;
#pragma unroll
      for (int j = 0; j < 4; ++j) {
        int row = m0 + wr * 64 + mf * 16 + l4 * 4 + j;
        float v = acc[mf][nf][j];
        if (MODE == 1) {
          v += bias[col];
          reinterpret_cast<float*>(Cout)[(size_t)row * Nn + col] = v;
        } else {
          reinterpret_cast<unsigned short*>(Cout)[(size_t)row * Nn + col] = f2b(v);
        }
      }
    }
}

// ---------------------------------------------------------------- LN + RoPE
// 4 rows per wave; lane group of 16 handles one row, 4 elems/lane (8B loads).
__global__ __launch_bounds__(256) void ln_rope(
    const unsigned short* __restrict__ qkv,  // [4096][3072] bf16
    const float* __restrict__ fcos, const float* __restrict__ fsin,  // [2048][64]
    unsigned short* __restrict__ qo, unsigned short* __restrict__ ko)  // [B*H][2048][64]
{
  const int rid = blockIdx.x * 16 + (threadIdx.x >> 4);
  const int q16 = threadIdx.x & 15;
  const int h = rid & 15;
  const int three = (rid >> 4) & 1;
  const int n = (rid >> 5) & 2047;
  const int b = rid >> 16;
  const int m = b * 2048 + n;
  const int d0 = q16 * 4;
  us4 raw = *reinterpret_cast<const us4*>(
      &qkv[(size_t)m * 3072 + three * 1024 + h * 64 + d0]);
  float v[4];
#pragma unroll
  for (int e = 0; e < 4; ++e) v[e] = b2f(raw[e]);
  float s = v[0] + v[1] + v[2] + v[3];
  float s2 = v[0] * v[0] + v[1] * v[1] + v[2] * v[2] + v[3] * v[3];
#pragma unroll
  for (int off = 8; off; off >>= 1) {
    s += __shfl_xor(s, off);
    s2 += __shfl_xor(s2, off);
  }
  float mu = s * (1.f / 64.f);
  float var = s2 * (1.f / 64.f) - mu * mu;
  float inv = rsqrtf(var + 1e-6f);
  float t[4], other[4];
#pragma unroll
  for (int e = 0; e < 4; ++e) t[e] = (v[e] - mu) * inv;
#pragma unroll
  for (int e = 0; e < 4; ++e) other[e] = __shfl_xor(t[e], 8);  // d ^ 32
  float4 c4 = *reinterpret_cast<const float4*>(&fcos[n * 64 + d0]);
  float4 s4 = *reinterpret_cast<const float4*>(&fsin[n * 64 + d0]);
  float sgn = (d0 < 32) ? -1.f : 1.f;
  us4 outv;
  outv[0] = f2b(t[0] * c4.x + sgn * other[0] * s4.x);
  outv[1] = f2b(t[1] * c4.y + sgn * other[1] * s4.y);
  outv[2] = f2b(t[2] * c4.z + sgn * other[2] * s4.z);
  outv[3] = f2b(t[3] * c4.w + sgn * other[3] * s4.w);
  unsigned short* dst = three ? ko : qo;
  *reinterpret_cast<us4*>(&dst[((size_t)(b * 16 + h) * 2048 + n) * 64 + d0]) = outv;
}

// ---------------------------------------------------------------- V transpose
__global__ __launch_bounds__(256) void v_transpose(
    const unsigned short* __restrict__ qkv, unsigned short* __restrict__ vt) {
  __shared__ unsigned short sh[64][72];
  const int tid = threadIdx.x;
  const int bid = blockIdx.x;
  const int nt = bid & 31;
  const int h = (bid >> 5) & 15;
  const int b = bid >> 9;
#pragma unroll
  for (int p = 0; p < 2; ++p) {
    int g = p * 256 + tid;
    int i = g >> 3, c = g & 7;
    us8 v = *reinterpret_cast<const us8*>(
        &qkv[(size_t)(b * 2048 + nt * 64 + i) * 3072 + 2048 + h * 64 + c * 8]);
    *reinterpret_cast<us8*>(&sh[i][c * 8]) = v;
  }
  __syncthreads();
  const int bh = b * 16 + h;
#pragma unroll
  for (int p = 0; p < 2; ++p) {
    int g = p * 256 + tid;
    int d = g >> 3, c2 = g & 7;
    us8 v;
#pragma unroll
    for (int j = 0; j < 8; ++j) v[j] = sh[c2 * 8 + j][d];
    *reinterpret_cast<us8*>(&vt[((size_t)bh * 64 + d) * 2048 + nt * 64 + c2 * 8]) = v;
  }
}

// ---------------------------------------------------------------- attention
// 1 block = one (b,h) x 128-row Q tile. 4 waves x 32 q-rows (2 frags).
// KV tiles of 64, double-buffered via global_load_lds; 1 barrier per tile.
__global__ __launch_bounds__(256) void attn_kern(
    const unsigned short* __restrict__ Q,   // [B*H][2048][64]
    const unsigned short* __restrict__ Kk,  // [B*H][2048][64]
    const unsigned short* __restrict__ Vt,  // [B*H][64][2048]
    unsigned short* __restrict__ O)         // [B][2048][1024]
{
  __shared__ unsigned short k_sh[2][64 * 64];
  __shared__ unsigned short v_sh[2][64 * 64];
  __shared__ unsigned short p_sh[4][2][16][72];
  const int tid = threadIdx.x;
  const int lane = tid & 63;
  const int w = tid >> 6;
  const int l15 = lane & 15, l4 = lane >> 4;
  const int bid = blockIdx.x;
  const int qt = bid & 15;   // 2048/128 q-tiles
  const int bh = bid >> 4;
  const int h = bh & 15, b = bh >> 4;
  const unsigned short* qb = Q + (size_t)bh * 2048 * 64;
  const unsigned short* kb = Kk + (size_t)bh * 2048 * 64;
  const unsigned short* vb = Vt + (size_t)bh * 64 * 2048;
  const int q0 = qt * 128 + w * 32;

  bf16x8 aq[2][2];
#pragma unroll
  for (int qf = 0; qf < 2; ++qf)
#pragma unroll
    for (int ks = 0; ks < 2; ++ks)
      aq[qf][ks] = *reinterpret_cast<const bf16x8*>(
          &qb[(size_t)(q0 + qf * 16 + l15) * 64 + ks * 32 + l4 * 8]);

  f32x4 acc[2][4] = {};
  float mrow[2][4], lrow[2][4];
#pragma unroll
  for (int qf = 0; qf < 2; ++qf)
#pragma unroll
    for (int j = 0; j < 4; ++j) { mrow[qf][j] = -1e30f; lrow[qf][j] = 0.f; }

  const int r8 = lane >> 3, cc8 = lane & 7;
  // stage tile kt into buffer buf: 16 segments (8 K + 8 V) of 8 rows x 64 shorts
#define ATTN_STAGE(KT, BUF)                                                        \
  {                                                                                \
    _Pragma("unroll") for (int p = 0; p < 4; ++p) {                                \
      int sseg = p * 4 + w;                                                        \
      if (sseg < 8) {                                                              \
        int row = sseg * 8 + r8;                                                   \
        async_copy16(&k_sh[BUF][sseg * 512],                                       \
                     &kb[(size_t)((KT) * 64 + row) * 64 + ((cc8 ^ (row & 7)) << 3)]); \
      } else {                                                                     \
        int row = (sseg - 8) * 8 + r8;                                             \
        async_copy16(&v_sh[BUF][(sseg - 8) * 512],                                 \
                     &vb[(size_t)row * 2048 + (KT) * 64 + ((cc8 ^ (row & 7)) << 3)]); \
      }                                                                            \
    }                                                                              \
  }

  ATTN_STAGE(0, 0);
  __syncthreads();

  for (int kt = 0; kt < 32; ++kt) {
    const int cur = kt & 1;
    if (kt < 31) ATTN_STAGE(kt + 1, cur ^ 1);

    // K fragments (shared by both q-frags)
    bf16x8 bk[4][2];
#pragma unroll
    for (int nf = 0; nf < 4; ++nf) {
      int r = nf * 16 + l15;
#pragma unroll
      for (int ks = 0; ks < 2; ++ks) {
        int c = ks * 4 + l4;
        bk[nf][ks] = *reinterpret_cast<const bf16x8*>(&k_sh[cur][r * 64 + ((c ^ (r & 7)) << 3)]);
      }
    }
#pragma unroll
    for (int qf = 0; qf < 2; ++qf) {
      f32x4 s[4];
#pragma unroll
      for (int nf = 0; nf < 4; ++nf) {
        f32x4 z = {0.f, 0.f, 0.f, 0.f};
#pragma unroll
        for (int ks = 0; ks < 2; ++ks)
          z = __builtin_amdgcn_mfma_f32_16x16x32_bf16(aq[qf][ks], bk[nf][ks], z, 0, 0, 0);
        s[nf] = z * 0.18033688011112042f;  // D^-0.5 * log2(e); exp2 domain
      }
      float corr[4];
#pragma unroll
      for (int j = 0; j < 4; ++j) {
        float mx = fmaxf(fmaxf(s[0][j], s[1][j]), fmaxf(s[2][j], s[3][j]));
        mx = fmaxf(mx, __shfl_xor(mx, 1));
        mx = fmaxf(mx, __shfl_xor(mx, 2));
        mx = fmaxf(mx, __shfl_xor(mx, 4));
        mx = fmaxf(mx, __shfl_xor(mx, 8));
        float mn = fmaxf(mrow[qf][j], mx);
        corr[j] = exp2f(mrow[qf][j] - mn);
        mrow[qf][j] = mn;
      }
      float rs[4] = {0.f, 0.f, 0.f, 0.f};
#pragma unroll
      for (int nf = 0; nf < 4; ++nf)
#pragma unroll
        for (int j = 0; j < 4; ++j) {
          float pv = exp2f(s[nf][j] - mrow[qf][j]);
          s[nf][j] = pv;
          rs[j] += pv;
        }
#pragma unroll
      for (int j = 0; j < 4; ++j) {
        float t = rs[j];
        t += __shfl_xor(t, 1);
        t += __shfl_xor(t, 2);
        t += __shfl_xor(t, 4);
        t += __shfl_xor(t, 8);
        lrow[qf][j] = lrow[qf][j] * corr[j] + t;
#pragma unroll
        for (int nf = 0; nf < 4; ++nf) acc[qf][nf][j] *= corr[j];
      }
      // P -> per-wave LDS (A-fragment layout); in-wave lgkmcnt orders w/ reads
#pragma unroll
      for (int nf = 0; nf < 4; ++nf)
#pragma unroll
        for (int j = 0; j < 4; ++j)
          p_sh[w][qf][l4 * 4 + j][nf * 16 + l15] = f2b(s[nf][j]);
    }
    // V fragments + PV
    bf16x8 bv[4][2];
#pragma unroll
    for (int nf = 0; nf < 4; ++nf) {
      int r = nf * 16 + l15;
#pragma unroll
      for (int ks = 0; ks < 2; ++ks) {
        int c = ks * 4 + l4;
        bv[nf][ks] = *reinterpret_cast<const bf16x8*>(&v_sh[cur][r * 64 + ((c ^ (r & 7)) << 3)]);
      }
    }
#pragma unroll
    for (int qf = 0; qf < 2; ++qf) {
      bf16x8 ap[2];
#pragma unroll
      for (int ks = 0; ks < 2; ++ks)
        ap[ks] = *reinterpret_cast<const bf16x8*>(&p_sh[w][qf][l15][ks * 32 + l4 * 8]);
#pragma unroll
      for (int nf = 0; nf < 4; ++nf)
#pragma unroll
        for (int ks = 0; ks < 2; ++ks)
          acc[qf][nf] = __builtin_amdgcn_mfma_f32_16x16x32_bf16(ap[ks], bv[nf][ks], acc[qf][nf], 0, 0, 0);
    }
    __syncthreads();  // staging done + all waves done with buf[cur]
  }
#pragma unroll
  for (int qf = 0; qf < 2; ++qf)
#pragma unroll
    for (int nf = 0; nf < 4; ++nf)
#pragma unroll
      for (int j = 0; j < 4; ++j) {
        int row = q0 + qf * 16 + l4 * 4 + j;
        int d = nf * 16 + l15;
        O[((size_t)b * 2048 + row) * 1024 + h * 64 + d] = f2b(acc[qf][nf][j] / lrow[qf][j]);
      }
#undef ATTN_STAGE
}

// ---------------------------------------------------------------- launch
extern "C" void kernel_launch(void* const* d_in, const int* in_sizes, int n_in,
                              void* d_out, int out_size, void* d_ws, size_t ws_size,
                              hipStream_t stream) {
  (void)in_sizes; (void)n_in; (void)out_size; (void)ws_size;
  const float* x      = (const float*)d_in[0];
  const float* w_qkv  = (const float*)d_in[1];
  const float* w_proj = (const float*)d_in[2];
  const float* b_proj = (const float*)d_in[3];
  const float* fcos   = (const float*)d_in[4];
  const float* fsin   = (const float*)d_in[5];
  float* out = (float*)d_out;
  char* ws = (char*)d_ws;

  unsigned short* x_bf     = (unsigned short*)(ws + 0);         // 8 MB
  unsigned short* wqkv_bf  = (unsigned short*)(ws + 8388608);   // 6 MB
  unsigned short* wproj_bf = (unsigned short*)(ws + 14680064);  // 2 MB
  unsigned short* qkv_bf   = (unsigned short*)(ws + 16777216);  // 24 MB
  unsigned short* q_bf     = (unsigned short*)(ws + 41943040);  // 8 MB
  unsigned short* k_bf     = (unsigned short*)(ws + 50331648);  // 8 MB
  unsigned short* vt_bf    = (unsigned short*)(ws + 58720256);  // 8 MB
  unsigned short* ao_bf    = (unsigned short*)(ws + 67108864);  // 8 MB  (total 72 MB)

  cvt_bf16<<<2048, 256, 0, stream>>>(x, x_bf, 4096 * 1024 / 8);
  cvt_bf16<<<1536, 256, 0, stream>>>(w_qkv, wqkv_bf, 3072 * 1024 / 8);
  cvt_bf16<<<512, 256, 0, stream>>>(w_proj, wproj_bf, 1024 * 1024 / 8);
  gemm_bt<0><<<dim3(24, 32), 256, 0, stream>>>(x_bf, wqkv_bf, nullptr, qkv_bf, 4096, 3072, 1024);
  ln_rope<<<8192, 256, 0, stream>>>(qkv_bf, fcos, fsin, q_bf, k_bf);
  v_transpose<<<1024, 256, 0, stream>>>(qkv_bf, vt_bf);
  attn_kern<<<512, 256, 0, stream>>>(q_bf, k_bf, vt_bf, ao_bf);
  gemm_bt<1><<<dim3(8, 32), 256, 0, stream>>>(ao_bf, wproj_bf, b_proj, out, 4096, 1024, 1024);
}

// Round 4
// 165.171 us; speedup vs baseline: 1.2945x; 1.2945x over previous
//
#include <hip/hip_runtime.h>
#include <hip/hip_bf16.h>

// Problem constants: B=2, N=2048, C=1024, H=16, D=64  (head_dim)
// M = B*N = 4096 rows. qkv layout along 3C axis: three*1024 + h*64 + d.

typedef __bf16 bf16x8 __attribute__((ext_vector_type(8)));
typedef float f32x4 __attribute__((ext_vector_type(4)));
typedef float f32x16 __attribute__((ext_vector_type(16)));
typedef unsigned short us8 __attribute__((ext_vector_type(8)));
typedef unsigned short us4 __attribute__((ext_vector_type(4)));

static __device__ __forceinline__ unsigned short f2b(float f) {
  __hip_bfloat16 h = __float2bfloat16(f);
  return __builtin_bit_cast(unsigned short, h);
}
static __device__ __forceinline__ float b2f(unsigned short u) {
  __hip_bfloat16 h = __builtin_bit_cast(__hip_bfloat16, u);
  return __bfloat162float(h);
}

// async global->LDS, 16B per lane. LDS dest = wave-uniform base + lane*16.
static __device__ __forceinline__ void async_copy16(void* lds, const void* g) {
  __builtin_amdgcn_global_load_lds(
      (const __attribute__((address_space(1))) void*)g,
      (__attribute__((address_space(3))) void*)lds, 16, 0, 0);
}

static __device__ __forceinline__ unsigned cvt_pk_bf16(float lo, float hi) {
  unsigned r;
  asm("v_cvt_pk_bf16_f32 %0, %1, %2" : "=v"(r) : "v"(lo), "v"(hi));
  return r;
}
static __device__ __forceinline__ void swap32(unsigned& x, unsigned& y) {
  asm("v_permlane32_swap_b32 %0, %1" : "+v"(x), "+v"(y));
}

// ---------------------------------------------------------------- convert
__global__ __launch_bounds__(256) void cvt_bf16(
    const float* __restrict__ in, unsigned short* __restrict__ out, int n8) {
  int i = blockIdx.x * 256 + threadIdx.x;
  if (i >= n8) return;
  const float4* p = reinterpret_cast<const float4*>(in) + (size_t)i * 2;
  float4 a = p[0], b = p[1];
  us8 v;
  v[0] = f2b(a.x); v[1] = f2b(a.y); v[2] = f2b(a.z); v[3] = f2b(a.w);
  v[4] = f2b(b.x); v[5] = f2b(b.y); v[6] = f2b(b.z); v[7] = f2b(b.w);
  reinterpret_cast<us8*>(out)[i] = v;
}

// ---------------------------------------------------------------- GEMM (B^T)
template <int MODE>
__global__ __launch_bounds__(256) void gemm_bt(
    const unsigned short* __restrict__ A, const unsigned short* __restrict__ Bw,
    const float* __restrict__ bias, void* __restrict__ Cout,
    int M, int Nn, int K) {
  __shared__ unsigned short a_sh[128 * 32];
  __shared__ unsigned short b_sh[128 * 32];
  const int tid = threadIdx.x;
  const int lane = tid & 63;
  const int w = tid >> 6;
  const int wr = w >> 1, wc = w & 1;
  const int l15 = lane & 15, l4 = lane >> 4;
  const int m0 = blockIdx.y * 128;
  const int n0 = blockIdx.x * 128;

  f32x4 acc[4][4] = {};

  for (int k0 = 0; k0 < K; k0 += 32) {
#pragma unroll
    for (int p = 0; p < 4; ++p) {
      int s = p * 4 + w;
      int row = ((s & 7) << 4) + (lane >> 2);
      int c = lane & 3;
      int sw = (c ^ ((row >> 1) & 3)) << 3;
      if (s < 8)
        async_copy16(&a_sh[s * 512], &A[(size_t)(m0 + row) * K + k0 + sw]);
      else
        async_copy16(&b_sh[(s - 8) * 512], &Bw[(size_t)(n0 + row) * K + k0 + sw]);
    }
    __syncthreads();
    bf16x8 af[4], bfr[4];
#pragma unroll
    for (int mf = 0; mf < 4; ++mf) {
      int r = wr * 64 + mf * 16 + l15;
      af[mf] = *reinterpret_cast<const bf16x8*>(&a_sh[r * 32 + ((l4 ^ ((r >> 1) & 3)) << 3)]);
    }
#pragma unroll
    for (int nf = 0; nf < 4; ++nf) {
      int r = wc * 64 + nf * 16 + l15;
      bfr[nf] = *reinterpret_cast<const bf16x8*>(&b_sh[r * 32 + ((l4 ^ ((r >> 1) & 3)) << 3)]);
    }
#pragma unroll
    for (int mf = 0; mf < 4; ++mf)
#pragma unroll
      for (int nf = 0; nf < 4; ++nf)
        acc[mf][nf] = __builtin_amdgcn_mfma_f32_16x16x32_bf16(af[mf], bfr[nf], acc[mf][nf], 0, 0, 0);
    __syncthreads();
  }
#pragma unroll
  for (int mf = 0; mf < 4; ++mf)
#pragma unroll
    for (int nf = 0; nf < 4; ++nf) {
      int col = n0 + wc * 64 + nf * 16 + l15;
#pragma unroll
      for (int j = 0; j < 4; ++j) {
        int row = m0 + wr * 64 + mf * 16 + l4 * 4 + j;
        float v = acc[mf][nf][j];
        if (MODE == 1) {
          v += bias[col];
          reinterpret_cast<float*>(Cout)[(size_t)row * Nn + col] = v;
        } else {
          reinterpret_cast<unsigned short*>(Cout)[(size_t)row * Nn + col] = f2b(v);
        }
      }
    }
}

// ---------------------------------------------------------------- LN + RoPE
// 4 rows per wave; 16-lane group per row, 4 elems/lane. Q output pre-scaled
// by D^-0.5 * log2(e) (softmax computed in exp2 domain downstream).
__global__ __launch_bounds__(256) void ln_rope(
    const unsigned short* __restrict__ qkv,  // [4096][3072] bf16
    const float* __restrict__ fcos, const float* __restrict__ fsin,  // [2048][64]
    unsigned short* __restrict__ qo, unsigned short* __restrict__ ko)  // [B*H][2048][64]
{
  const int rid = blockIdx.x * 16 + (threadIdx.x >> 4);
  const int q16 = threadIdx.x & 15;
  const int h = rid & 15;
  const int three = (rid >> 4) & 1;
  const int n = (rid >> 5) & 2047;
  const int b = rid >> 16;
  const int m = b * 2048 + n;
  const int d0 = q16 * 4;
  us4 raw = *reinterpret_cast<const us4*>(
      &qkv[(size_t)m * 3072 + three * 1024 + h * 64 + d0]);
  float v[4];
#pragma unroll
  for (int e = 0; e < 4; ++e) v[e] = b2f(raw[e]);
  float s = v[0] + v[1] + v[2] + v[3];
  float s2 = v[0] * v[0] + v[1] * v[1] + v[2] * v[2] + v[3] * v[3];
#pragma unroll
  for (int off = 8; off; off >>= 1) {
    s += __shfl_xor(s, off);
    s2 += __shfl_xor(s2, off);
  }
  float mu = s * (1.f / 64.f);
  float var = s2 * (1.f / 64.f) - mu * mu;
  float inv = rsqrtf(var + 1e-6f);
  float t[4], other[4];
#pragma unroll
  for (int e = 0; e < 4; ++e) t[e] = (v[e] - mu) * inv;
#pragma unroll
  for (int e = 0; e < 4; ++e) other[e] = __shfl_xor(t[e], 8);  // d ^ 32
  float4 c4 = *reinterpret_cast<const float4*>(&fcos[n * 64 + d0]);
  float4 s4 = *reinterpret_cast<const float4*>(&fsin[n * 64 + d0]);
  float sgn = (d0 < 32) ? -1.f : 1.f;
  float sc = three ? 1.f : 0.18033688011112042f;  // q: D^-0.5 * log2(e)
  us4 outv;
  outv[0] = f2b(sc * (t[0] * c4.x + sgn * other[0] * s4.x));
  outv[1] = f2b(sc * (t[1] * c4.y + sgn * other[1] * s4.y));
  outv[2] = f2b(sc * (t[2] * c4.z + sgn * other[2] * s4.z));
  outv[3] = f2b(sc * (t[3] * c4.w + sgn * other[3] * s4.w));
  unsigned short* dst = three ? ko : qo;
  *reinterpret_cast<us4*>(&dst[((size_t)(b * 16 + h) * 2048 + n) * 64 + d0]) = outv;
}

// ---------------------------------------------------------------- V transpose
__global__ __launch_bounds__(256) void v_transpose(
    const unsigned short* __restrict__ qkv, unsigned short* __restrict__ vt) {
  __shared__ unsigned short sh[64][72];
  const int tid = threadIdx.x;
  const int bid = blockIdx.x;
  const int nt = bid & 31;
  const int h = (bid >> 5) & 15;
  const int b = bid >> 9;
#pragma unroll
  for (int p = 0; p < 2; ++p) {
    int g = p * 256 + tid;
    int i = g >> 3, c = g & 7;
    us8 v = *reinterpret_cast<const us8*>(
        &qkv[(size_t)(b * 2048 + nt * 64 + i) * 3072 + 2048 + h * 64 + c * 8]);
    *reinterpret_cast<us8*>(&sh[i][c * 8]) = v;
  }
  __syncthreads();
  const int bh = b * 16 + h;
#pragma unroll
  for (int p = 0; p < 2; ++p) {
    int g = p * 256 + tid;
    int d = g >> 3, c2 = g & 7;
    us8 v;
#pragma unroll
    for (int j = 0; j < 8; ++j) v[j] = sh[c2 * 8 + j][d];
    *reinterpret_cast<us8*>(&vt[((size_t)bh * 64 + d) * 2048 + nt * 64 + c2 * 8]) = v;
  }
}

// ---------------------------------------------------------------- attention
// Swapped-QK^T 32x32 structure: 1 block = (b,h) x 128 q-rows, 4 waves x 32 q.
// S^T = mfma32(K, Q): lane holds full k-column for q = lane&31 in registers;
// softmax in-lane + 1 shfl; P->B-frag via cvt_pk + permlane32_swap (no LDS).
// O^T += mfma32(V^T, P^T). KV tiles of 64, double-buffered global_load_lds.
__global__ __launch_bounds__(256) void attn_kern(
    const unsigned short* __restrict__ Q,   // [B*H][2048][64]  (pre-scaled)
    const unsigned short* __restrict__ Kk,  // [B*H][2048][64]
    const unsigned short* __restrict__ Vt,  // [B*H][64][2048]
    unsigned short* __restrict__ O)         // [B][2048][1024]
{
  __shared__ unsigned short k_sh[2][64 * 64];
  __shared__ unsigned short v_sh[2][64 * 64];
  const int tid = threadIdx.x;
  const int lane = tid & 63;
  const int w = tid >> 6;
  const int l31 = lane & 31;
  const int H = lane >> 5;
  const int bid = blockIdx.x;
  const int wid = (bid & 7) * 64 + (bid >> 3);  // XCD swizzle: 4 bh per XCD
  const int qt = wid & 15;
  const int bh = wid >> 4;
  const int h = bh & 15, b = bh >> 4;
  const unsigned short* qb = Q + (size_t)bh * 2048 * 64;
  const unsigned short* kb = Kk + (size_t)bh * 2048 * 64;
  const unsigned short* vb = Vt + (size_t)bh * 64 * 2048;
  const int tok = qt * 128 + w * 32 + l31;

  // Q B-frags: lane holds Q[tok][c*16 + H*8 .. +7]
  bf16x8 qf[4];
#pragma unroll
  for (int c = 0; c < 4; ++c)
    qf[c] = *reinterpret_cast<const bf16x8*>(&qb[(size_t)tok * 64 + c * 16 + H * 8]);

  f32x16 oT[2] = {};
  float mr = -1e30f, lr = 0.f;

  const int r8 = lane >> 3, cc8 = lane & 7;
#define ATTN_STAGE(KT, BUF)                                                        \
  {                                                                                \
    _Pragma("unroll") for (int p = 0; p < 4; ++p) {                                \
      int sseg = p * 4 + w;                                                        \
      if (sseg < 8) {                                                              \
        int row = sseg * 8 + r8;                                                   \
        async_copy16(&k_sh[BUF][sseg * 512],                                       \
                     &kb[(size_t)((KT) * 64 + row) * 64 + ((cc8 ^ (row & 7)) << 3)]); \
      } else {                                                                     \
        int row = (sseg - 8) * 8 + r8;                                             \
        async_copy16(&v_sh[BUF][(sseg - 8) * 512],                                 \
                     &vb[(size_t)row * 2048 + (KT) * 64 + ((cc8 ^ (row & 7)) << 3)]); \
      }                                                                            \
    }                                                                              \
  }

  ATTN_STAGE(0, 0);
  __syncthreads();

  for (int kt = 0; kt < 32; ++kt) {
    const int cur = kt & 1;
    if (kt < 31) ATTN_STAGE(kt + 1, cur ^ 1);

    // S^T[k][q]: accumulate over d (4 chunks of 16)
    f32x16 sT0 = {}, sT1 = {};
#pragma unroll
    for (int c = 0; c < 4; ++c) {
      int ch0 = (2 * c + H);
      {
        int r = l31;  // k-rows 0..31
        bf16x8 ka = *reinterpret_cast<const bf16x8*>(
            &k_sh[cur][r * 64 + ((ch0 ^ (r & 7)) << 3)]);
        sT0 = __builtin_amdgcn_mfma_f32_32x32x16_bf16(ka, qf[c], sT0, 0, 0, 0);
      }
      {
        int r = 32 + l31;  // k-rows 32..63
        bf16x8 ka = *reinterpret_cast<const bf16x8*>(
            &k_sh[cur][r * 64 + ((ch0 ^ (r & 7)) << 3)]);
        sT1 = __builtin_amdgcn_mfma_f32_32x32x16_bf16(ka, qf[c], sT1, 0, 0, 0);
      }
    }
    // online softmax for q = lane&31 (values already in exp2 domain)
    float tmax = sT0[0];
#pragma unroll
    for (int r = 1; r < 16; ++r) tmax = fmaxf(tmax, sT0[r]);
#pragma unroll
    for (int r = 0; r < 16; ++r) tmax = fmaxf(tmax, sT1[r]);
    tmax = fmaxf(tmax, __shfl_xor(tmax, 32));
    float mn = fmaxf(mr, tmax);
    float corr = exp2f(mr - mn);
    mr = mn;
    float tsum = 0.f;
#pragma unroll
    for (int r = 0; r < 16; ++r) {
      float p = exp2f(sT0[r] - mn);
      sT0[r] = p;
      tsum += p;
    }
#pragma unroll
    for (int r = 0; r < 16; ++r) {
      float p = exp2f(sT1[r] - mn);
      sT1[r] = p;
      tsum += p;
    }
    tsum += __shfl_xor(tsum, 32);
    lr = lr * corr + tsum;
#pragma unroll
    for (int r = 0; r < 16; ++r) { oT[0][r] *= corr; oT[1][r] *= corr; }

    // P^T -> B-operand frags (in-register): chunk m covers k = 16m..16m+15
    bf16x8 pB[4];
#pragma unroll
    for (int mi = 0; mi < 4; ++mi) {
      const int mm = mi & 1;
      unsigned x0, x1, y0, y1;
      if (mi < 2) {
        x0 = cvt_pk_bf16(sT0[8 * mm + 0], sT0[8 * mm + 1]);
        x1 = cvt_pk_bf16(sT0[8 * mm + 2], sT0[8 * mm + 3]);
        y0 = cvt_pk_bf16(sT0[8 * mm + 4], sT0[8 * mm + 5]);
        y1 = cvt_pk_bf16(sT0[8 * mm + 6], sT0[8 * mm + 7]);
      } else {
        x0 = cvt_pk_bf16(sT1[8 * mm + 0], sT1[8 * mm + 1]);
        x1 = cvt_pk_bf16(sT1[8 * mm + 2], sT1[8 * mm + 3]);
        y0 = cvt_pk_bf16(sT1[8 * mm + 4], sT1[8 * mm + 5]);
        y1 = cvt_pk_bf16(sT1[8 * mm + 6], sT1[8 * mm + 7]);
      }
      swap32(x0, y0);
      swap32(x1, y1);
      int4 packed = {(int)x0, (int)x1, (int)y0, (int)y1};
      pB[mi] = __builtin_bit_cast(bf16x8, packed);
    }
    // O^T += V^T * P^T
#pragma unroll
    for (int dt = 0; dt < 2; ++dt) {
      int r = dt * 32 + l31;
#pragma unroll
      for (int mi = 0; mi < 4; ++mi) {
        int ch = (2 * mi + H) ^ (r & 7);
        bf16x8 va = *reinterpret_cast<const bf16x8*>(&v_sh[cur][r * 64 + (ch << 3)]);
        oT[dt] = __builtin_amdgcn_mfma_f32_32x32x16_bf16(va, pB[mi], oT[dt], 0, 0, 0);
      }
    }
    __syncthreads();
  }
  // epilogue: O[b, tok, h*64 + d], d = (reg&3) + 8*(reg>>2) + 4*H + 32*dt
  float invl = 1.f / lr;
#pragma unroll
  for (int dt = 0; dt < 2; ++dt)
#pragma unroll
    for (int rb = 0; rb < 4; ++rb) {
      us4 ov;
#pragma unroll
      for (int j = 0; j < 4; ++j) ov[j] = f2b(oT[dt][rb * 4 + j] * invl);
      *reinterpret_cast<us4*>(
          &O[((size_t)b * 2048 + tok) * 1024 + h * 64 + 32 * dt + 8 * rb + 4 * H]) = ov;
    }
#undef ATTN_STAGE
}

// ---------------------------------------------------------------- launch
extern "C" void kernel_launch(void* const* d_in, const int* in_sizes, int n_in,
                              void* d_out, int out_size, void* d_ws, size_t ws_size,
                              hipStream_t stream) {
  (void)in_sizes; (void)n_in; (void)out_size; (void)ws_size;
  const float* x      = (const float*)d_in[0];
  const float* w_qkv  = (const float*)d_in[1];
  const float* w_proj = (const float*)d_in[2];
  const float* b_proj = (const float*)d_in[3];
  const float* fcos   = (const float*)d_in[4];
  const float* fsin   = (const float*)d_in[5];
  float* out = (float*)d_out;
  char* ws = (char*)d_ws;

  unsigned short* x_bf     = (unsigned short*)(ws + 0);         // 8 MB
  unsigned short* wqkv_bf  = (unsigned short*)(ws + 8388608);   // 6 MB
  unsigned short* wproj_bf = (unsigned short*)(ws + 14680064);  // 2 MB
  unsigned short* qkv_bf   = (unsigned short*)(ws + 16777216);  // 24 MB
  unsigned short* q_bf     = (unsigned short*)(ws + 41943040);  // 8 MB
  unsigned short* k_bf     = (unsigned short*)(ws + 50331648);  // 8 MB
  unsigned short* vt_bf    = (unsigned short*)(ws + 58720256);  // 8 MB
  unsigned short* ao_bf    = (unsigned short*)(ws + 67108864);  // 8 MB  (total 72 MB)

  cvt_bf16<<<2048, 256, 0, stream>>>(x, x_bf, 4096 * 1024 / 8);
  cvt_bf16<<<1536, 256, 0, stream>>>(w_qkv, wqkv_bf, 3072 * 1024 / 8);
  cvt_bf16<<<512, 256, 0, stream>>>(w_proj, wproj_bf, 1024 * 1024 / 8);
  gemm_bt<0><<<dim3(24, 32), 256, 0, stream>>>(x_bf, wqkv_bf, nullptr, qkv_bf, 4096, 3072, 1024);
  ln_rope<<<8192, 256, 0, stream>>>(qkv_bf, fcos, fsin, q_bf, k_bf);
  v_transpose<<<1024, 256, 0, stream>>>(qkv_bf, vt_bf);
  attn_kern<<<512, 256, 0, stream>>>(q_bf, k_bf, vt_bf, ao_bf);
  gemm_bt<1><<<dim3(8, 32), 256, 0, stream>>>(ao_bf, wproj_bf, b_proj, out, 4096, 1024, 1024);
}

// Round 5
// 151.739 us; speedup vs baseline: 1.4091x; 1.0885x over previous
//
#include <hip/hip_runtime.h>
#include <hip/hip_bf16.h>

// Problem constants: B=2, N=2048, C=1024, H=16, D=64  (head_dim)
// M = B*N = 4096 rows. qkv layout along 3C axis: three*1024 + h*64 + d.

typedef __bf16 bf16x8 __attribute__((ext_vector_type(8)));
typedef float f32x4 __attribute__((ext_vector_type(4)));
typedef float f32x16 __attribute__((ext_vector_type(16)));
typedef unsigned short us8 __attribute__((ext_vector_type(8)));
typedef unsigned short us4 __attribute__((ext_vector_type(4)));

static __device__ __forceinline__ unsigned short f2b(float f) {
  __hip_bfloat16 h = __float2bfloat16(f);
  return __builtin_bit_cast(unsigned short, h);
}
static __device__ __forceinline__ float b2f(unsigned short u) {
  __hip_bfloat16 h = __builtin_bit_cast(__hip_bfloat16, u);
  return __bfloat162float(h);
}

// async global->LDS, 16B per lane. LDS dest = wave-uniform base + lane*16.
static __device__ __forceinline__ void async_copy16(void* lds, const void* g) {
  __builtin_amdgcn_global_load_lds(
      (const __attribute__((address_space(1))) void*)g,
      (__attribute__((address_space(3))) void*)lds, 16, 0, 0);
}

static __device__ __forceinline__ unsigned cvt_pk_bf16(float lo, float hi) {
  unsigned r;
  asm("v_cvt_pk_bf16_f32 %0, %1, %2" : "=v"(r) : "v"(lo), "v"(hi));
  return r;
}
static __device__ __forceinline__ void swap32(unsigned& x, unsigned& y) {
  asm("v_permlane32_swap_b32 %0, %1" : "+v"(x), "+v"(y));
}
static __device__ __forceinline__ float max3f(float a, float b, float c) {
  float d;
  asm("v_max3_f32 %0, %1, %2, %3" : "=v"(d) : "v"(a), "v"(b), "v"(c));
  return d;
}
// balanced max of 16 (5+2+1 ops, depth 3)
static __device__ __forceinline__ float vmax16(const f32x16& v) {
  float a = max3f(v[0], v[1], v[2]);
  float b = max3f(v[3], v[4], v[5]);
  float c = max3f(v[6], v[7], v[8]);
  float d = max3f(v[9], v[10], v[11]);
  float e = max3f(v[12], v[13], v[14]);
  float x = max3f(a, b, c);
  float y = max3f(d, e, v[15]);
  return fmaxf(x, y);
}

// ---------------------------------------------------------------- convert
__global__ __launch_bounds__(256) void cvt_bf16(
    const float* __restrict__ in, unsigned short* __restrict__ out, int n8) {
  int i = blockIdx.x * 256 + threadIdx.x;
  if (i >= n8) return;
  const float4* p = reinterpret_cast<const float4*>(in) + (size_t)i * 2;
  float4 a = p[0], b = p[1];
  us8 v;
  v[0] = f2b(a.x); v[1] = f2b(a.y); v[2] = f2b(a.z); v[3] = f2b(a.w);
  v[4] = f2b(b.x); v[5] = f2b(b.y); v[6] = f2b(b.z); v[7] = f2b(b.w);
  reinterpret_cast<us8*>(out)[i] = v;
}

// ---------------------------------------------------------------- GEMM (B^T)
// C[m][n] = sum_k A[m][k] * Bw[n][k]. 128x128 tile, BK=64, 4 waves (2x2).
template <int MODE>
__global__ __launch_bounds__(256) void gemm_bt(
    const unsigned short* __restrict__ A, const unsigned short* __restrict__ Bw,
    const float* __restrict__ bias, void* __restrict__ Cout,
    int M, int Nn, int K) {
  __shared__ unsigned short a_sh[128 * 64];
  __shared__ unsigned short b_sh[128 * 64];
  const int tid = threadIdx.x;
  const int lane = tid & 63;
  const int w = tid >> 6;
  const int wr = w >> 1, wc = w & 1;
  const int l15 = lane & 15, l4 = lane >> 4;
  const int m0 = blockIdx.y * 128;
  const int n0 = blockIdx.x * 128;
  const int r8 = lane >> 3, c8 = lane & 7;

  f32x4 acc[4][4] = {};

  for (int k0 = 0; k0 < K; k0 += 64) {
    // stage 32 KB: 32 segments of 1KB (8 rows x 128B); 8 per wave
#pragma unroll
    for (int p = 0; p < 8; ++p) {
      int s = p * 4 + w;
      if (s < 16) {
        int row = s * 8 + r8;
        async_copy16(&a_sh[s * 512],
                     &A[(size_t)(m0 + row) * K + k0 + ((c8 ^ (row & 7)) << 3)]);
      } else {
        int s2 = s - 16;
        int row = s2 * 8 + r8;
        async_copy16(&b_sh[s2 * 512],
                     &Bw[(size_t)(n0 + row) * K + k0 + ((c8 ^ (row & 7)) << 3)]);
      }
    }
    __syncthreads();
#pragma unroll
    for (int kk = 0; kk < 2; ++kk) {
      bf16x8 af[4], bfr[4];
#pragma unroll
      for (int mf = 0; mf < 4; ++mf) {
        int r = wr * 64 + mf * 16 + l15;
        af[mf] = *reinterpret_cast<const bf16x8*>(
            &a_sh[r * 64 + (((kk * 4 + l4) ^ (r & 7)) << 3)]);
      }
#pragma unroll
      for (int nf = 0; nf < 4; ++nf) {
        int r = wc * 64 + nf * 16 + l15;
        bfr[nf] = *reinterpret_cast<const bf16x8*>(
            &b_sh[r * 64 + (((kk * 4 + l4) ^ (r & 7)) << 3)]);
      }
#pragma unroll
      for (int mf = 0; mf < 4; ++mf)
#pragma unroll
        for (int nf = 0; nf < 4; ++nf)
          acc[mf][nf] = __builtin_amdgcn_mfma_f32_16x16x32_bf16(af[mf], bfr[nf], acc[mf][nf], 0, 0, 0);
    }
    __syncthreads();
  }
#pragma unroll
  for (int mf = 0; mf < 4; ++mf)
#pragma unroll
    for (int nf = 0; nf < 4; ++nf) {
      int col = n0 + wc * 64 + nf * 16 + l15;
#pragma unroll
      for (int j = 0; j < 4; ++j) {
        int row = m0 + wr * 64 + mf * 16 + l4 * 4 + j;
        float v = acc[mf][nf][j];
        if (MODE == 1) {
          v += bias[col];
          reinterpret_cast<float*>(Cout)[(size_t)row * Nn + col] = v;
        } else {
          reinterpret_cast<unsigned short*>(Cout)[(size_t)row * Nn + col] = f2b(v);
        }
      }
    }
}

// ---------------------------------------------------------------- LN + RoPE
// 4 rows per wave; 16-lane group per row, 4 elems/lane. Q output pre-scaled
// by D^-0.5 * log2(e) (softmax computed in exp2 domain downstream).
__global__ __launch_bounds__(256) void ln_rope(
    const unsigned short* __restrict__ qkv,  // [4096][3072] bf16
    const float* __restrict__ fcos, const float* __restrict__ fsin,  // [2048][64]
    unsigned short* __restrict__ qo, unsigned short* __restrict__ ko)  // [B*H][2048][64]
{
  const int rid = blockIdx.x * 16 + (threadIdx.x >> 4);
  const int q16 = threadIdx.x & 15;
  const int h = rid & 15;
  const int three = (rid >> 4) & 1;
  const int n = (rid >> 5) & 2047;
  const int b = rid >> 16;
  const int m = b * 2048 + n;
  const int d0 = q16 * 4;
  us4 raw = *reinterpret_cast<const us4*>(
      &qkv[(size_t)m * 3072 + three * 1024 + h * 64 + d0]);
  float v[4];
#pragma unroll
  for (int e = 0; e < 4; ++e) v[e] = b2f(raw[e]);
  float s = v[0] + v[1] + v[2] + v[3];
  float s2 = v[0] * v[0] + v[1] * v[1] + v[2] * v[2] + v[3] * v[3];
#pragma unroll
  for (int off = 8; off; off >>= 1) {
    s += __shfl_xor(s, off);
    s2 += __shfl_xor(s2, off);
  }
  float mu = s * (1.f / 64.f);
  float var = s2 * (1.f / 64.f) - mu * mu;
  float inv = rsqrtf(var + 1e-6f);
  float t[4], other[4];
#pragma unroll
  for (int e = 0; e < 4; ++e) t[e] = (v[e] - mu) * inv;
#pragma unroll
  for (int e = 0; e < 4; ++e) other[e] = __shfl_xor(t[e], 8);  // d ^ 32
  float4 c4 = *reinterpret_cast<const float4*>(&fcos[n * 64 + d0]);
  float4 s4 = *reinterpret_cast<const float4*>(&fsin[n * 64 + d0]);
  float sgn = (d0 < 32) ? -1.f : 1.f;
  float sc = three ? 1.f : 0.18033688011112042f;  // q: D^-0.5 * log2(e)
  us4 outv;
  outv[0] = f2b(sc * (t[0] * c4.x + sgn * other[0] * s4.x));
  outv[1] = f2b(sc * (t[1] * c4.y + sgn * other[1] * s4.y));
  outv[2] = f2b(sc * (t[2] * c4.z + sgn * other[2] * s4.z));
  outv[3] = f2b(sc * (t[3] * c4.w + sgn * other[3] * s4.w));
  unsigned short* dst = three ? ko : qo;
  *reinterpret_cast<us4*>(&dst[((size_t)(b * 16 + h) * 2048 + n) * 64 + d0]) = outv;
}

// ---------------------------------------------------------------- V transpose
__global__ __launch_bounds__(256) void v_transpose(
    const unsigned short* __restrict__ qkv, unsigned short* __restrict__ vt) {
  __shared__ unsigned short sh[64][72];
  const int tid = threadIdx.x;
  const int bid = blockIdx.x;
  const int nt = bid & 31;
  const int h = (bid >> 5) & 15;
  const int b = bid >> 9;
#pragma unroll
  for (int p = 0; p < 2; ++p) {
    int g = p * 256 + tid;
    int i = g >> 3, c = g & 7;
    us8 v = *reinterpret_cast<const us8*>(
        &qkv[(size_t)(b * 2048 + nt * 64 + i) * 3072 + 2048 + h * 64 + c * 8]);
    *reinterpret_cast<us8*>(&sh[i][c * 8]) = v;
  }
  __syncthreads();
  const int bh = b * 16 + h;
#pragma unroll
  for (int p = 0; p < 2; ++p) {
    int g = p * 256 + tid;
    int d = g >> 3, c2 = g & 7;
    us8 v;
#pragma unroll
    for (int j = 0; j < 8; ++j) v[j] = sh[c2 * 8 + j][d];
    *reinterpret_cast<us8*>(&vt[((size_t)bh * 64 + d) * 2048 + nt * 64 + c2 * 8]) = v;
  }
}

// ---------------------------------------------------------------- attention
// Swapped-QK^T 32x32 structure, KVBLK=128: 1 block = (b,h) x 128 q-rows,
// 4 waves x 32 q. S^T = mfma32(K, Q); softmax in-lane + 1 shfl; defer-rescale
// (THR=8); P->B-frag via cvt_pk + permlane32_swap. O^T += mfma32(V^T, P^T).
__global__ __launch_bounds__(256) void attn_kern(
    const unsigned short* __restrict__ Q,   // [B*H][2048][64]  (pre-scaled)
    const unsigned short* __restrict__ Kk,  // [B*H][2048][64]
    const unsigned short* __restrict__ Vt,  // [B*H][64][2048]
    unsigned short* __restrict__ O)         // [B][2048][1024]
{
  __shared__ unsigned short k_sh[2][128 * 64];
  __shared__ unsigned short v_sh[2][64 * 128];
  const int tid = threadIdx.x;
  const int lane = tid & 63;
  const int w = tid >> 6;
  const int l31 = lane & 31;
  const int H = lane >> 5;
  const int bid = blockIdx.x;
  const int wid = (bid & 7) * 64 + (bid >> 3);  // XCD swizzle: 4 bh per XCD
  const int qt = wid & 15;
  const int bh = wid >> 4;
  const int h = bh & 15, b = bh >> 4;
  const unsigned short* qb = Q + (size_t)bh * 2048 * 64;
  const unsigned short* kb = Kk + (size_t)bh * 2048 * 64;
  const unsigned short* vb = Vt + (size_t)bh * 64 * 2048;
  const int tok = qt * 128 + w * 32 + l31;

  // Q B-frags: lane holds Q[tok][c*16 + H*8 .. +7]
  bf16x8 qf[4];
#pragma unroll
  for (int c = 0; c < 4; ++c)
    qf[c] = *reinterpret_cast<const bf16x8*>(&qb[(size_t)tok * 64 + c * 16 + H * 8]);

  f32x16 oT[2] = {};
  float mr = -1e30f, lr = 0.f;

  const int r8 = lane >> 3, cc8 = lane & 7;    // K staging
  const int r4 = lane >> 4, cc16 = lane & 15;  // V staging
  // stage one 128-key tile: K 16 segs (8 rows x 128B), V^T 16 segs (4 rows x 256B)
#define ATTN_STAGE(KT, BUF)                                                           \
  {                                                                                   \
    _Pragma("unroll") for (int p = 0; p < 8; ++p) {                                   \
      int sseg = p * 4 + w;                                                           \
      if (sseg < 16) {                                                                \
        int row = sseg * 8 + r8;                                                      \
        async_copy16(&k_sh[BUF][sseg * 512],                                          \
                     &kb[(size_t)((KT) * 128 + row) * 64 + ((cc8 ^ (row & 7)) << 3)]);   \
      } else {                                                                        \
        int s2 = sseg - 16;                                                           \
        int row = s2 * 4 + r4;                                                        \
        async_copy16(&v_sh[BUF][s2 * 512],                                            \
                     &vb[(size_t)row * 2048 + (KT) * 128 + ((cc16 ^ (row & 7)) << 3)]);  \
      }                                                                               \
    }                                                                                 \
  }

  ATTN_STAGE(0, 0);
  __syncthreads();

  for (int kt = 0; kt < 16; ++kt) {
    const int cur = kt & 1;
    if (kt < 15) ATTN_STAGE(kt + 1, cur ^ 1);

    // S^T[k][q] for k-blocks t: 0..3, accumulate over d (4 chunks of 16)
    f32x16 sT[4] = {};
#pragma unroll
    for (int c = 0; c < 4; ++c) {
      int ch0 = 2 * c + H;
#pragma unroll
      for (int t = 0; t < 4; ++t) {
        int r = t * 32 + l31;
        bf16x8 ka = *reinterpret_cast<const bf16x8*>(
            &k_sh[cur][r * 64 + (((ch0) ^ (r & 7)) << 3)]);
        sT[t] = __builtin_amdgcn_mfma_f32_32x32x16_bf16(ka, qf[c], sT[t], 0, 0, 0);
      }
    }
    // online softmax for q = lane&31 (exp2 domain); defer-rescale THR=8
    float tmax = fmaxf(fmaxf(vmax16(sT[0]), vmax16(sT[1])),
                       fmaxf(vmax16(sT[2]), vmax16(sT[3])));
    tmax = fmaxf(tmax, __shfl_xor(tmax, 32));
    if (__any(tmax > mr + 8.f)) {
      float mn = fmaxf(mr, tmax);
      float corr = exp2f(mr - mn);
      mr = mn;
      lr *= corr;
#pragma unroll
      for (int r = 0; r < 16; ++r) { oT[0][r] *= corr; oT[1][r] *= corr; }
    }
    float tsum = 0.f;
#pragma unroll
    for (int t = 0; t < 4; ++t)
#pragma unroll
      for (int r = 0; r < 16; ++r) {
        float p = exp2f(sT[t][r] - mr);
        sT[t][r] = p;
        tsum += p;
      }
    tsum += __shfl_xor(tsum, 32);
    lr += tsum;

    // P^T -> B-operand frags (in-register): pB[2t+half] covers k=16(2t+half)..+15
    bf16x8 pB[8];
#pragma unroll
    for (int t = 0; t < 4; ++t)
#pragma unroll
      for (int half = 0; half < 2; ++half) {
        const int base = 8 * half;
        unsigned x0 = cvt_pk_bf16(sT[t][base + 0], sT[t][base + 1]);
        unsigned x1 = cvt_pk_bf16(sT[t][base + 2], sT[t][base + 3]);
        unsigned y0 = cvt_pk_bf16(sT[t][base + 4], sT[t][base + 5]);
        unsigned y1 = cvt_pk_bf16(sT[t][base + 6], sT[t][base + 7]);
        swap32(x0, y0);
        swap32(x1, y1);
        int4 packed = {(int)x0, (int)x1, (int)y0, (int)y1};
        pB[2 * t + half] = __builtin_bit_cast(bf16x8, packed);
      }
    // O^T += V^T * P^T
#pragma unroll
    for (int dt = 0; dt < 2; ++dt) {
      int r = dt * 32 + l31;
#pragma unroll
      for (int mi = 0; mi < 8; ++mi) {
        int ch = (mi * 2 + H) ^ (r & 7);
        bf16x8 va = *reinterpret_cast<const bf16x8*>(&v_sh[cur][r * 128 + (ch << 3)]);
        oT[dt] = __builtin_amdgcn_mfma_f32_32x32x16_bf16(va, pB[mi], oT[dt], 0, 0, 0);
      }
    }
    __syncthreads();
  }
  // epilogue: O[b, tok, h*64 + d], d = (reg&3) + 8*(reg>>2) + 4*H + 32*dt
  float invl = 1.f / lr;
#pragma unroll
  for (int dt = 0; dt < 2; ++dt)
#pragma unroll
    for (int rb = 0; rb < 4; ++rb) {
      us4 ov;
#pragma unroll
      for (int j = 0; j < 4; ++j) ov[j] = f2b(oT[dt][rb * 4 + j] * invl);
      *reinterpret_cast<us4*>(
          &O[((size_t)b * 2048 + tok) * 1024 + h * 64 + 32 * dt + 8 * rb + 4 * H]) = ov;
    }
#undef ATTN_STAGE
}

// ---------------------------------------------------------------- launch
extern "C" void kernel_launch(void* const* d_in, const int* in_sizes, int n_in,
                              void* d_out, int out_size, void* d_ws, size_t ws_size,
                              hipStream_t stream) {
  (void)in_sizes; (void)n_in; (void)out_size; (void)ws_size;
  const float* x      = (const float*)d_in[0];
  const float* w_qkv  = (const float*)d_in[1];
  const float* w_proj = (const float*)d_in[2];
  const float* b_proj = (const float*)d_in[3];
  const float* fcos   = (const float*)d_in[4];
  const float* fsin   = (const float*)d_in[5];
  float* out = (float*)d_out;
  char* ws = (char*)d_ws;

  unsigned short* x_bf     = (unsigned short*)(ws + 0);         // 8 MB
  unsigned short* wqkv_bf  = (unsigned short*)(ws + 8388608);   // 6 MB
  unsigned short* wproj_bf = (unsigned short*)(ws + 14680064);  // 2 MB
  unsigned short* qkv_bf   = (unsigned short*)(ws + 16777216);  // 24 MB
  unsigned short* q_bf     = (unsigned short*)(ws + 41943040);  // 8 MB
  unsigned short* k_bf     = (unsigned short*)(ws + 50331648);  // 8 MB
  unsigned short* vt_bf    = (unsigned short*)(ws + 58720256);  // 8 MB
  unsigned short* ao_bf    = (unsigned short*)(ws + 67108864);  // 8 MB  (total 72 MB)

  cvt_bf16<<<2048, 256, 0, stream>>>(x, x_bf, 4096 * 1024 / 8);
  cvt_bf16<<<1536, 256, 0, stream>>>(w_qkv, wqkv_bf, 3072 * 1024 / 8);
  cvt_bf16<<<512, 256, 0, stream>>>(w_proj, wproj_bf, 1024 * 1024 / 8);
  gemm_bt<0><<<dim3(24, 32), 256, 0, stream>>>(x_bf, wqkv_bf, nullptr, qkv_bf, 4096, 3072, 1024);
  ln_rope<<<8192, 256, 0, stream>>>(qkv_bf, fcos, fsin, q_bf, k_bf);
  v_transpose<<<1024, 256, 0, stream>>>(qkv_bf, vt_bf);
  attn_kern<<<512, 256, 0, stream>>>(q_bf, k_bf, vt_bf, ao_bf);
  gemm_bt<1><<<dim3(8, 32), 256, 0, stream>>>(ao_bf, wproj_bf, b_proj, out, 4096, 1024, 1024);
}

// Round 6
// 131.000 us; speedup vs baseline: 1.6322x; 1.1583x over previous
//
#include <hip/hip_runtime.h>
#include <hip/hip_bf16.h>

// Problem constants: B=2, N=2048, C=1024, H=16, D=64  (head_dim)
// M = B*N = 4096 rows. qkv layout along 3C axis: three*1024 + h*64 + d.

typedef __bf16 bf16x8 __attribute__((ext_vector_type(8)));
typedef float f32x4 __attribute__((ext_vector_type(4)));
typedef float f32x16 __attribute__((ext_vector_type(16)));
typedef unsigned short us8 __attribute__((ext_vector_type(8)));
typedef unsigned short us4 __attribute__((ext_vector_type(4)));

static __device__ __forceinline__ unsigned short f2b(float f) {
  __hip_bfloat16 h = __float2bfloat16(f);
  return __builtin_bit_cast(unsigned short, h);
}
static __device__ __forceinline__ float b2f(unsigned short u) {
  __hip_bfloat16 h = __builtin_bit_cast(__hip_bfloat16, u);
  return __bfloat162float(h);
}

#if __has_builtin(__builtin_amdgcn_exp2f)
static __device__ __forceinline__ float fast_exp2(float x) { return __builtin_amdgcn_exp2f(x); }
#else
static __device__ __forceinline__ float fast_exp2(float x) { return exp2f(x); }
#endif

// async global->LDS, 16B per lane. LDS dest = wave-uniform base + lane*16.
static __device__ __forceinline__ void async_copy16(void* lds, const void* g) {
  __builtin_amdgcn_global_load_lds(
      (const __attribute__((address_space(1))) void*)g,
      (__attribute__((address_space(3))) void*)lds, 16, 0, 0);
}

static __device__ __forceinline__ unsigned cvt_pk_bf16(float lo, float hi) {
  unsigned r;
  asm("v_cvt_pk_bf16_f32 %0, %1, %2" : "=v"(r) : "v"(lo), "v"(hi));
  return r;
}
static __device__ __forceinline__ void swap32(unsigned& x, unsigned& y) {
  asm("v_permlane32_swap_b32 %0, %1" : "+v"(x), "+v"(y));
}
static __device__ __forceinline__ float max3f(float a, float b, float c) {
  float d;
  asm("v_max3_f32 %0, %1, %2, %3" : "=v"(d) : "v"(a), "v"(b), "v"(c));
  return d;
}
// balanced max of 16 (5+2+1 ops, depth 3)
static __device__ __forceinline__ float vmax16(const f32x16& v) {
  float a = max3f(v[0], v[1], v[2]);
  float b = max3f(v[3], v[4], v[5]);
  float c = max3f(v[6], v[7], v[8]);
  float d = max3f(v[9], v[10], v[11]);
  float e = max3f(v[12], v[13], v[14]);
  float x = max3f(a, b, c);
  float y = max3f(d, e, v[15]);
  return fmaxf(x, y);
}

// ---------------------------------------------------------------- convert
__global__ __launch_bounds__(256) void cvt_bf16(
    const float* __restrict__ in, unsigned short* __restrict__ out, int n8) {
  int i = blockIdx.x * 256 + threadIdx.x;
  if (i >= n8) return;
  const float4* p = reinterpret_cast<const float4*>(in) + (size_t)i * 2;
  float4 a = p[0], b = p[1];
  us8 v;
  v[0] = f2b(a.x); v[1] = f2b(a.y); v[2] = f2b(a.z); v[3] = f2b(a.w);
  v[4] = f2b(b.x); v[5] = f2b(b.y); v[6] = f2b(b.z); v[7] = f2b(b.w);
  reinterpret_cast<us8*>(out)[i] = v;
}

// ---------------------------------------------------------------- GEMM (B^T)
// C[m][n] = sum_k A[m][k] * Bw[n][k]. 128x128 tile, BK=64, 4 waves (2x2).
template <int MODE>
__global__ __launch_bounds__(256, 2) void gemm_bt(
    const unsigned short* __restrict__ A, const unsigned short* __restrict__ Bw,
    const float* __restrict__ bias, void* __restrict__ Cout,
    int M, int Nn, int K) {
  __shared__ unsigned short a_sh[128 * 64];
  __shared__ unsigned short b_sh[128 * 64];
  const int tid = threadIdx.x;
  const int lane = tid & 63;
  const int w = tid >> 6;
  const int wr = w >> 1, wc = w & 1;
  const int l15 = lane & 15, l4 = lane >> 4;
  const int m0 = blockIdx.y * 128;
  const int n0 = blockIdx.x * 128;
  const int r8 = lane >> 3, c8 = lane & 7;

  f32x4 acc[4][4] = {};

  for (int k0 = 0; k0 < K; k0 += 64) {
    // stage 32 KB: 32 segments of 1KB (8 rows x 128B); 8 per wave
#pragma unroll
    for (int p = 0; p < 8; ++p) {
      int s = p * 4 + w;
      if (s < 16) {
        int row = s * 8 + r8;
        async_copy16(&a_sh[s * 512],
                     &A[(size_t)(m0 + row) * K + k0 + ((c8 ^ (row & 7)) << 3)]);
      } else {
        int s2 = s - 16;
        int row = s2 * 8 + r8;
        async_copy16(&b_sh[s2 * 512],
                     &Bw[(size_t)(n0 + row) * K + k0 + ((c8 ^ (row & 7)) << 3)]);
      }
    }
    __syncthreads();
#pragma unroll
    for (int kk = 0; kk < 2; ++kk) {
      bf16x8 af[4], bfr[4];
#pragma unroll
      for (int mf = 0; mf < 4; ++mf) {
        int r = wr * 64 + mf * 16 + l15;
        af[mf] = *reinterpret_cast<const bf16x8*>(
            &a_sh[r * 64 + (((kk * 4 + l4) ^ (r & 7)) << 3)]);
      }
#pragma unroll
      for (int nf = 0; nf < 4; ++nf) {
        int r = wc * 64 + nf * 16 + l15;
        bfr[nf] = *reinterpret_cast<const bf16x8*>(
            &b_sh[r * 64 + (((kk * 4 + l4) ^ (r & 7)) << 3)]);
      }
#pragma unroll
      for (int mf = 0; mf < 4; ++mf)
#pragma unroll
        for (int nf = 0; nf < 4; ++nf)
          acc[mf][nf] = __builtin_amdgcn_mfma_f32_16x16x32_bf16(af[mf], bfr[nf], acc[mf][nf], 0, 0, 0);
    }
    __syncthreads();
  }
#pragma unroll
  for (int mf = 0; mf < 4; ++mf)
#pragma unroll
    for (int nf = 0; nf < 4; ++nf) {
      int col = n0 + wc * 64 + nf * 16 + l15;
#pragma unroll
      for (int j = 0; j < 4; ++j) {
        int row = m0 + wr * 64 + mf * 16 + l4 * 4 + j;
        float v = acc[mf][nf][j];
        if (MODE == 1) {
          v += bias[col];
          reinterpret_cast<float*>(Cout)[(size_t)row * Nn + col] = v;
        } else {
          reinterpret_cast<unsigned short*>(Cout)[(size_t)row * Nn + col] = f2b(v);
        }
      }
    }
}

// ---------------------------------------------------------------- LN + RoPE
// 4 rows per wave; 16-lane group per row, 4 elems/lane. Q output pre-scaled
// by D^-0.5 * log2(e) (softmax computed in exp2 domain downstream).
__global__ __launch_bounds__(256) void ln_rope(
    const unsigned short* __restrict__ qkv,  // [4096][3072] bf16
    const float* __restrict__ fcos, const float* __restrict__ fsin,  // [2048][64]
    unsigned short* __restrict__ qo, unsigned short* __restrict__ ko)  // [B*H][2048][64]
{
  const int rid = blockIdx.x * 16 + (threadIdx.x >> 4);
  const int q16 = threadIdx.x & 15;
  const int h = rid & 15;
  const int three = (rid >> 4) & 1;
  const int n = (rid >> 5) & 2047;
  const int b = rid >> 16;
  const int m = b * 2048 + n;
  const int d0 = q16 * 4;
  us4 raw = *reinterpret_cast<const us4*>(
      &qkv[(size_t)m * 3072 + three * 1024 + h * 64 + d0]);
  float v[4];
#pragma unroll
  for (int e = 0; e < 4; ++e) v[e] = b2f(raw[e]);
  float s = v[0] + v[1] + v[2] + v[3];
  float s2 = v[0] * v[0] + v[1] * v[1] + v[2] * v[2] + v[3] * v[3];
#pragma unroll
  for (int off = 8; off; off >>= 1) {
    s += __shfl_xor(s, off);
    s2 += __shfl_xor(s2, off);
  }
  float mu = s * (1.f / 64.f);
  float var = s2 * (1.f / 64.f) - mu * mu;
  float inv = rsqrtf(var + 1e-6f);
  float t[4], other[4];
#pragma unroll
  for (int e = 0; e < 4; ++e) t[e] = (v[e] - mu) * inv;
#pragma unroll
  for (int e = 0; e < 4; ++e) other[e] = __shfl_xor(t[e], 8);  // d ^ 32
  float4 c4 = *reinterpret_cast<const float4*>(&fcos[n * 64 + d0]);
  float4 s4 = *reinterpret_cast<const float4*>(&fsin[n * 64 + d0]);
  float sgn = (d0 < 32) ? -1.f : 1.f;
  float sc = three ? 1.f : 0.18033688011112042f;  // q: D^-0.5 * log2(e)
  us4 outv;
  outv[0] = f2b(sc * (t[0] * c4.x + sgn * other[0] * s4.x));
  outv[1] = f2b(sc * (t[1] * c4.y + sgn * other[1] * s4.y));
  outv[2] = f2b(sc * (t[2] * c4.z + sgn * other[2] * s4.z));
  outv[3] = f2b(sc * (t[3] * c4.w + sgn * other[3] * s4.w));
  unsigned short* dst = three ? ko : qo;
  *reinterpret_cast<us4*>(&dst[((size_t)(b * 16 + h) * 2048 + n) * 64 + d0]) = outv;
}

// ---------------------------------------------------------------- V transpose
__global__ __launch_bounds__(256) void v_transpose(
    const unsigned short* __restrict__ qkv, unsigned short* __restrict__ vt) {
  __shared__ unsigned short sh[64][72];
  const int tid = threadIdx.x;
  const int bid = blockIdx.x;
  const int nt = bid & 31;
  const int h = (bid >> 5) & 15;
  const int b = bid >> 9;
#pragma unroll
  for (int p = 0; p < 2; ++p) {
    int g = p * 256 + tid;
    int i = g >> 3, c = g & 7;
    us8 v = *reinterpret_cast<const us8*>(
        &qkv[(size_t)(b * 2048 + nt * 64 + i) * 3072 + 2048 + h * 64 + c * 8]);
    *reinterpret_cast<us8*>(&sh[i][c * 8]) = v;
  }
  __syncthreads();
  const int bh = b * 16 + h;
#pragma unroll
  for (int p = 0; p < 2; ++p) {
    int g = p * 256 + tid;
    int d = g >> 3, c2 = g & 7;
    us8 v;
#pragma unroll
    for (int j = 0; j < 8; ++j) v[j] = sh[c2 * 8 + j][d];
    *reinterpret_cast<us8*>(&vt[((size_t)bh * 64 + d) * 2048 + nt * 64 + c2 * 8]) = v;
  }
}

// ---------------------------------------------------------------- attention
// Swapped-QK^T 32x32 structure, KVBLK=128: 1 block = (b,h) x 128 q-rows,
// 4 waves x 32 q. S^T = mfma32(K, Q); softmax in-lane + 1 shfl; defer-rescale
// (THR=8); P->B-frag via cvt_pk + permlane32_swap. O^T += mfma32(V^T, P^T).
// launch_bounds (256,2): LDS caps us at 2 blocks/CU anyway; give the register
// allocator the full 256-VGPR budget so sT/oT stay in arch VGPRs (no accvgpr
// ping-pong / scratch).
__global__ __launch_bounds__(256, 2) void attn_kern(
    const unsigned short* __restrict__ Q,   // [B*H][2048][64]  (pre-scaled)
    const unsigned short* __restrict__ Kk,  // [B*H][2048][64]
    const unsigned short* __restrict__ Vt,  // [B*H][64][2048]
    unsigned short* __restrict__ O)         // [B][2048][1024]
{
  __shared__ unsigned short k_sh[2][128 * 64];
  __shared__ unsigned short v_sh[2][64 * 128];
  const int tid = threadIdx.x;
  const int lane = tid & 63;
  const int w = tid >> 6;
  const int l31 = lane & 31;
  const int H = lane >> 5;
  const int bid = blockIdx.x;
  const int wid = (bid & 7) * 64 + (bid >> 3);  // XCD swizzle: 4 bh per XCD
  const int qt = wid & 15;
  const int bh = wid >> 4;
  const int h = bh & 15, b = bh >> 4;
  const unsigned short* qb = Q + (size_t)bh * 2048 * 64;
  const unsigned short* kb = Kk + (size_t)bh * 2048 * 64;
  const unsigned short* vb = Vt + (size_t)bh * 64 * 2048;
  const int tok = qt * 128 + w * 32 + l31;

  // Q B-frags: lane holds Q[tok][c*16 + H*8 .. +7]
  bf16x8 qf[4];
#pragma unroll
  for (int c = 0; c < 4; ++c)
    qf[c] = *reinterpret_cast<const bf16x8*>(&qb[(size_t)tok * 64 + c * 16 + H * 8]);

  f32x16 oT[2] = {};
  float mr = -1e30f, lr = 0.f;

  const int r8 = lane >> 3, cc8 = lane & 7;    // K staging
  const int r4 = lane >> 4, cc16 = lane & 15;  // V staging
  // stage one 128-key tile: K 16 segs (8 rows x 128B), V^T 16 segs (4 rows x 256B)
#define ATTN_STAGE(KT, BUF)                                                           \
  {                                                                                   \
    _Pragma("unroll") for (int p = 0; p < 8; ++p) {                                   \
      int sseg = p * 4 + w;                                                           \
      if (sseg < 16) {                                                                \
        int row = sseg * 8 + r8;                                                      \
        async_copy16(&k_sh[BUF][sseg * 512],                                          \
                     &kb[(size_t)((KT) * 128 + row) * 64 + ((cc8 ^ (row & 7)) << 3)]);   \
      } else {                                                                        \
        int s2 = sseg - 16;                                                           \
        int row = s2 * 4 + r4;                                                        \
        async_copy16(&v_sh[BUF][s2 * 512],                                            \
                     &vb[(size_t)row * 2048 + (KT) * 128 + ((cc16 ^ (row & 7)) << 3)]);  \
      }                                                                               \
    }                                                                                 \
  }

  ATTN_STAGE(0, 0);
  __syncthreads();

  for (int kt = 0; kt < 16; ++kt) {
    const int cur = kt & 1;
    if (kt < 15) ATTN_STAGE(kt + 1, cur ^ 1);

    // S^T[k][q] for k-blocks t: 0..3, accumulate over d (4 chunks of 16)
    f32x16 sT[4] = {};
#pragma unroll
    for (int c = 0; c < 4; ++c) {
      int ch0 = 2 * c + H;
#pragma unroll
      for (int t = 0; t < 4; ++t) {
        int r = t * 32 + l31;
        bf16x8 ka = *reinterpret_cast<const bf16x8*>(
            &k_sh[cur][r * 64 + (((ch0) ^ (r & 7)) << 3)]);
        sT[t] = __builtin_amdgcn_mfma_f32_32x32x16_bf16(ka, qf[c], sT[t], 0, 0, 0);
      }
    }
    // online softmax for q = lane&31 (exp2 domain); defer-rescale THR=8
    float tmax = fmaxf(fmaxf(vmax16(sT[0]), vmax16(sT[1])),
                       fmaxf(vmax16(sT[2]), vmax16(sT[3])));
    tmax = fmaxf(tmax, __shfl_xor(tmax, 32));
    if (__any(tmax > mr + 8.f)) {
      float mn = fmaxf(mr, tmax);
      float corr = fast_exp2(mr - mn);
      mr = mn;
      lr *= corr;
#pragma unroll
      for (int r = 0; r < 16; ++r) { oT[0][r] *= corr; oT[1][r] *= corr; }
    }
    float tsum = 0.f;
#pragma unroll
    for (int t = 0; t < 4; ++t)
#pragma unroll
      for (int r = 0; r < 16; ++r) {
        float p = fast_exp2(sT[t][r] - mr);
        sT[t][r] = p;
        tsum += p;
      }
    tsum += __shfl_xor(tsum, 32);
    lr += tsum;

    // P^T -> B-operand frags (in-register): pB[2t+half] covers k=16(2t+half)..+15
    bf16x8 pB[8];
#pragma unroll
    for (int t = 0; t < 4; ++t)
#pragma unroll
      for (int half = 0; half < 2; ++half) {
        const int base = 8 * half;
        unsigned x0 = cvt_pk_bf16(sT[t][base + 0], sT[t][base + 1]);
        unsigned x1 = cvt_pk_bf16(sT[t][base + 2], sT[t][base + 3]);
        unsigned y0 = cvt_pk_bf16(sT[t][base + 4], sT[t][base + 5]);
        unsigned y1 = cvt_pk_bf16(sT[t][base + 6], sT[t][base + 7]);
        swap32(x0, y0);
        swap32(x1, y1);
        int4 packed = {(int)x0, (int)x1, (int)y0, (int)y1};
        pB[2 * t + half] = __builtin_bit_cast(bf16x8, packed);
      }
    // O^T += V^T * P^T
#pragma unroll
    for (int dt = 0; dt < 2; ++dt) {
      int r = dt * 32 + l31;
#pragma unroll
      for (int mi = 0; mi < 8; ++mi) {
        int ch = (mi * 2 + H) ^ (r & 7);
        bf16x8 va = *reinterpret_cast<const bf16x8*>(&v_sh[cur][r * 128 + (ch << 3)]);
        oT[dt] = __builtin_amdgcn_mfma_f32_32x32x16_bf16(va, pB[mi], oT[dt], 0, 0, 0);
      }
    }
    __syncthreads();
  }
  // epilogue: O[b, tok, h*64 + d], d = (reg&3) + 8*(reg>>2) + 4*H + 32*dt
  float invl = 1.f / lr;
#pragma unroll
  for (int dt = 0; dt < 2; ++dt)
#pragma unroll
    for (int rb = 0; rb < 4; ++rb) {
      us4 ov;
#pragma unroll
      for (int j = 0; j < 4; ++j) ov[j] = f2b(oT[dt][rb * 4 + j] * invl);
      *reinterpret_cast<us4*>(
          &O[((size_t)b * 2048 + tok) * 1024 + h * 64 + 32 * dt + 8 * rb + 4 * H]) = ov;
    }
#undef ATTN_STAGE
}

// ---------------------------------------------------------------- launch
extern "C" void kernel_launch(void* const* d_in, const int* in_sizes, int n_in,
                              void* d_out, int out_size, void* d_ws, size_t ws_size,
                              hipStream_t stream) {
  (void)in_sizes; (void)n_in; (void)out_size; (void)ws_size;
  const float* x      = (const float*)d_in[0];
  const float* w_qkv  = (const float*)d_in[1];
  const float* w_proj = (const float*)d_in[2];
  const float* b_proj = (const float*)d_in[3];
  const float* fcos   = (const float*)d_in[4];
  const float* fsin   = (const float*)d_in[5];
  float* out = (float*)d_out;
  char* ws = (char*)d_ws;

  unsigned short* x_bf     = (unsigned short*)(ws + 0);         // 8 MB
  unsigned short* wqkv_bf  = (unsigned short*)(ws + 8388608);   // 6 MB
  unsigned short* wproj_bf = (unsigned short*)(ws + 14680064);  // 2 MB
  unsigned short* qkv_bf   = (unsigned short*)(ws + 16777216);  // 24 MB
  unsigned short* q_bf     = (unsigned short*)(ws + 41943040);  // 8 MB
  unsigned short* k_bf     = (unsigned short*)(ws + 50331648);  // 8 MB
  unsigned short* vt_bf    = (unsigned short*)(ws + 58720256);  // 8 MB
  unsigned short* ao_bf    = (unsigned short*)(ws + 67108864);  // 8 MB  (total 72 MB)

  cvt_bf16<<<2048, 256, 0, stream>>>(x, x_bf, 4096 * 1024 / 8);
  cvt_bf16<<<1536, 256, 0, stream>>>(w_qkv, wqkv_bf, 3072 * 1024 / 8);
  cvt_bf16<<<512, 256, 0, stream>>>(w_proj, wproj_bf, 1024 * 1024 / 8);
  gemm_bt<0><<<dim3(24, 32), 256, 0, stream>>>(x_bf, wqkv_bf, nullptr, qkv_bf, 4096, 3072, 1024);
  ln_rope<<<8192, 256, 0, stream>>>(qkv_bf, fcos, fsin, q_bf, k_bf);
  v_transpose<<<1024, 256, 0, stream>>>(qkv_bf, vt_bf);
  attn_kern<<<512, 256, 0, stream>>>(q_bf, k_bf, vt_bf, ao_bf);
  gemm_bt<1><<<dim3(8, 32), 256, 0, stream>>>(ao_bf, wproj_bf, b_proj, out, 4096, 1024, 1024);
}

// Round 7
// 124.377 us; speedup vs baseline: 1.7191x; 1.0533x over previous
//
#include <hip/hip_runtime.h>
#include <hip/hip_bf16.h>

// Problem constants: B=2, N=2048, C=1024, H=16, D=64  (head_dim)
// M = B*N = 4096 rows. qkv col layout: three*1024 + h*64 + d.

typedef __bf16 bf16x8 __attribute__((ext_vector_type(8)));
typedef float f32x4 __attribute__((ext_vector_type(4)));
typedef float f32x16 __attribute__((ext_vector_type(16)));
typedef unsigned short us8 __attribute__((ext_vector_type(8)));
typedef unsigned short us4 __attribute__((ext_vector_type(4)));

static __device__ __forceinline__ unsigned short f2b(float f) {
  __hip_bfloat16 h = __float2bfloat16(f);
  return __builtin_bit_cast(unsigned short, h);
}
static __device__ __forceinline__ float b2f(unsigned short u) {
  __hip_bfloat16 h = __builtin_bit_cast(__hip_bfloat16, u);
  return __bfloat162float(h);
}

#if __has_builtin(__builtin_amdgcn_exp2f)
static __device__ __forceinline__ float fast_exp2(float x) { return __builtin_amdgcn_exp2f(x); }
#else
static __device__ __forceinline__ float fast_exp2(float x) { return exp2f(x); }
#endif

// async global->LDS, 16B per lane. LDS dest = wave-uniform base + lane*16.
static __device__ __forceinline__ void async_copy16(void* lds, const void* g) {
  __builtin_amdgcn_global_load_lds(
      (const __attribute__((address_space(1))) void*)g,
      (__attribute__((address_space(3))) void*)lds, 16, 0, 0);
}

static __device__ __forceinline__ unsigned cvt_pk_bf16(float lo, float hi) {
  unsigned r;
  asm("v_cvt_pk_bf16_f32 %0, %1, %2" : "=v"(r) : "v"(lo), "v"(hi));
  return r;
}
static __device__ __forceinline__ void swap32(unsigned& x, unsigned& y) {
  asm("v_permlane32_swap_b32 %0, %1" : "+v"(x), "+v"(y));
}
static __device__ __forceinline__ float max3f(float a, float b, float c) {
  float d;
  asm("v_max3_f32 %0, %1, %2, %3" : "=v"(d) : "v"(a), "v"(b), "v"(c));
  return d;
}
// balanced max of 16 (5+2+1 ops, depth 3)
static __device__ __forceinline__ float vmax16(const f32x16& v) {
  float a = max3f(v[0], v[1], v[2]);
  float b = max3f(v[3], v[4], v[5]);
  float c = max3f(v[6], v[7], v[8]);
  float d = max3f(v[9], v[10], v[11]);
  float e = max3f(v[12], v[13], v[14]);
  float x = max3f(a, b, c);
  float y = max3f(d, e, v[15]);
  return fmaxf(x, y);
}

// ---------------------------------------------------------------- convert
__global__ __launch_bounds__(256) void cvt_bf16(
    const float* __restrict__ in, unsigned short* __restrict__ out, int n8) {
  int i = blockIdx.x * 256 + threadIdx.x;
  if (i >= n8) return;
  const float4* p = reinterpret_cast<const float4*>(in) + (size_t)i * 2;
  float4 a = p[0], b = p[1];
  us8 v;
  v[0] = f2b(a.x); v[1] = f2b(a.y); v[2] = f2b(a.z); v[3] = f2b(a.w);
  v[4] = f2b(b.x); v[5] = f2b(b.y); v[6] = f2b(b.z); v[7] = f2b(b.w);
  reinterpret_cast<us8*>(out)[i] = v;
}

// ---------------------------------------------------------------- QKV GEMM + LN + RoPE + V-transpose
// C[m][n] = sum_k x[m][k] * w_qkv[n][k]; 128x128 tile, BK=64, 4 waves (2x2).
// Epilogue: three<2 -> per-head LayerNorm (over d=64, one wave's col block) +
// RoPE (+ q pre-scale) -> q_bf/k_bf [bh][n][d]; three==2 -> v transposed to
// vt [bh][d][n]. All writes routed through per-wave LDS retranspose buffers
// (wave-local, no barrier) for coalesced 16B stores.
__global__ __launch_bounds__(256, 2) void gemm_qkv(
    const unsigned short* __restrict__ A,   // x_bf [4096][1024]
    const unsigned short* __restrict__ Bw,  // wqkv_bf [3072][1024]
    const float* __restrict__ fcos, const float* __restrict__ fsin,  // [2048][64]
    unsigned short* __restrict__ qo, unsigned short* __restrict__ ko,  // [32][2048][64]
    unsigned short* __restrict__ vt)  // [32][64][2048]
{
  __shared__ unsigned short a_sh[128 * 64];
  __shared__ unsigned short b_sh[128 * 64];
  const int tid = threadIdx.x;
  const int lane = tid & 63;
  const int w = tid >> 6;
  const int wr = w >> 1, wc = w & 1;
  const int l15 = lane & 15, l4 = lane >> 4;
  const int m0 = blockIdx.y * 128;
  const int n0 = blockIdx.x * 128;
  const int r8 = lane >> 3, c8 = lane & 7;
  const int K = 1024;

  f32x4 acc[4][4] = {};

  for (int k0 = 0; k0 < K; k0 += 64) {
#pragma unroll
    for (int p = 0; p < 8; ++p) {
      int s = p * 4 + w;
      if (s < 16) {
        int row = s * 8 + r8;
        async_copy16(&a_sh[s * 512],
                     &A[(size_t)(m0 + row) * K + k0 + ((c8 ^ (row & 7)) << 3)]);
      } else {
        int s2 = s - 16;
        int row = s2 * 8 + r8;
        async_copy16(&b_sh[s2 * 512],
                     &Bw[(size_t)(n0 + row) * K + k0 + ((c8 ^ (row & 7)) << 3)]);
      }
    }
    __syncthreads();
#pragma unroll
    for (int kk = 0; kk < 2; ++kk) {
      bf16x8 af[4], bfr[4];
#pragma unroll
      for (int mf = 0; mf < 4; ++mf) {
        int r = wr * 64 + mf * 16 + l15;
        af[mf] = *reinterpret_cast<const bf16x8*>(
            &a_sh[r * 64 + (((kk * 4 + l4) ^ (r & 7)) << 3)]);
      }
#pragma unroll
      for (int nf = 0; nf < 4; ++nf) {
        int r = wc * 64 + nf * 16 + l15;
        bfr[nf] = *reinterpret_cast<const bf16x8*>(
            &b_sh[r * 64 + (((kk * 4 + l4) ^ (r & 7)) << 3)]);
      }
#pragma unroll
      for (int mf = 0; mf < 4; ++mf)
#pragma unroll
        for (int nf = 0; nf < 4; ++nf)
          acc[mf][nf] = __builtin_amdgcn_mfma_f32_16x16x32_bf16(af[mf], bfr[nf], acc[mf][nf], 0, 0, 0);
    }
    __syncthreads();
  }

  // ---- fused epilogue ----
  const int colbase = n0 + wc * 64;       // head-aligned (64 | colbase)
  const int three = colbase >> 10;        // uniform per wave
  const int hh = (colbase >> 6) & 15;
  const int b_ = m0 >> 11;                // uniform per block (128 | 2048)
  const int nbase = (m0 & 2047) + wr * 64;
  unsigned short* ep = ((w < 2) ? a_sh : b_sh) + (w & 1) * 4096;  // 8KB/wave
  const int cch = lane & 7, rb2 = lane >> 3;

  if (three < 2) {
    const float sc = three ? 1.f : 0.18033688011112042f;  // q: D^-0.5 * log2(e)
#pragma unroll
    for (int mf = 0; mf < 4; ++mf) {
#pragma unroll
      for (int j = 0; j < 4; ++j) {
        float a0 = acc[mf][0][j], a1 = acc[mf][1][j];
        float a2 = acc[mf][2][j], a3 = acc[mf][3][j];
        float s1 = (a0 + a1) + (a2 + a3);
        float s2 = (a0 * a0 + a1 * a1) + (a2 * a2 + a3 * a3);
#pragma unroll
        for (int off = 8; off; off >>= 1) {
          s1 += __shfl_xor(s1, off);
          s2 += __shfl_xor(s2, off);
        }
        float mu = s1 * (1.f / 64.f);
        float inv = rsqrtf(s2 * (1.f / 64.f) - mu * mu + 1e-6f);
        int rloc = mf * 16 + l4 * 4 + j;  // row within wave block (0..63)
        int n = nbase + rloc;
        const float* cp = &fcos[(size_t)n * 64];
        const float* sp = &fsin[(size_t)n * 64];
#pragma unroll
        for (int nf = 0; nf < 4; ++nf) {
          int d = nf * 16 + l15;
          float t = (acc[mf][nf][j] - mu) * inv;
          float tp = (acc[mf][nf ^ 2][j] - mu) * inv;  // partner d^32
          float r = sc * (t * cp[d] + ((nf < 2) ? -tp : tp) * sp[d]);
          ep[rloc * 64 + ((((d >> 3) ^ (rloc & 7)) << 3) | (d & 7))] = f2b(r);
        }
      }
    }
    unsigned short* dst =
        (three ? ko : qo) + (size_t)(b_ * 16 + hh) * 2048 * 64;
#pragma unroll
    for (int i = 0; i < 8; ++i) {
      int row = i * 8 + rb2;
      us8 vd = *reinterpret_cast<const us8*>(
          &ep[row * 64 + ((cch ^ (row & 7)) << 3)]);
      *reinterpret_cast<us8*>(&dst[(size_t)(nbase + row) * 64 + cch * 8]) = vd;
    }
  } else {
    // v: stash as [d][n_local] (transpose), then coalesced store to vt[bh][d][n]
#pragma unroll
    for (int mf = 0; mf < 4; ++mf)
#pragma unroll
      for (int nf = 0; nf < 4; ++nf) {
        int d = nf * 16 + l15;
#pragma unroll
        for (int j = 0; j < 4; ++j) {
          int nl = mf * 16 + l4 * 4 + j;
          ep[d * 64 + ((((nl >> 3) ^ (d & 7)) << 3) | (nl & 7))] =
              f2b(acc[mf][nf][j]);
        }
      }
    unsigned short* dst = vt + (size_t)(b_ * 16 + hh) * 64 * 2048;
#pragma unroll
    for (int i = 0; i < 8; ++i) {
      int d = i * 8 + rb2;
      us8 vd = *reinterpret_cast<const us8*>(
          &ep[d * 64 + ((cch ^ (d & 7)) << 3)]);
      *reinterpret_cast<us8*>(&dst[(size_t)d * 2048 + nbase + cch * 8]) = vd;
    }
  }
}

// ---------------------------------------------------------------- proj GEMM
// out[m][n] = sum_k ao[m][k] * w_proj[n][k] + bias[n], fp32 out.
__global__ __launch_bounds__(256, 2) void gemm_proj(
    const unsigned short* __restrict__ A, const unsigned short* __restrict__ Bw,
    const float* __restrict__ bias, float* __restrict__ Cout,
    int M, int Nn, int K) {
  __shared__ unsigned short a_sh[128 * 64];
  __shared__ unsigned short b_sh[128 * 64];
  const int tid = threadIdx.x;
  const int lane = tid & 63;
  const int w = tid >> 6;
  const int wr = w >> 1, wc = w & 1;
  const int l15 = lane & 15, l4 = lane >> 4;
  const int m0 = blockIdx.y * 128;
  const int n0 = blockIdx.x * 128;
  const int r8 = lane >> 3, c8 = lane & 7;

  f32x4 acc[4][4] = {};

  for (int k0 = 0; k0 < K; k0 += 64) {
#pragma unroll
    for (int p = 0; p < 8; ++p) {
      int s = p * 4 + w;
      if (s < 16) {
        int row = s * 8 + r8;
        async_copy16(&a_sh[s * 512],
                     &A[(size_t)(m0 + row) * K + k0 + ((c8 ^ (row & 7)) << 3)]);
      } else {
        int s2 = s - 16;
        int row = s2 * 8 + r8;
        async_copy16(&b_sh[s2 * 512],
                     &Bw[(size_t)(n0 + row) * K + k0 + ((c8 ^ (row & 7)) << 3)]);
      }
    }
    __syncthreads();
#pragma unroll
    for (int kk = 0; kk < 2; ++kk) {
      bf16x8 af[4], bfr[4];
#pragma unroll
      for (int mf = 0; mf < 4; ++mf) {
        int r = wr * 64 + mf * 16 + l15;
        af[mf] = *reinterpret_cast<const bf16x8*>(
            &a_sh[r * 64 + (((kk * 4 + l4) ^ (r & 7)) << 3)]);
      }
#pragma unroll
      for (int nf = 0; nf < 4; ++nf) {
        int r = wc * 64 + nf * 16 + l15;
        bfr[nf] = *reinterpret_cast<const bf16x8*>(
            &b_sh[r * 64 + (((kk * 4 + l4) ^ (r & 7)) << 3)]);
      }
#pragma unroll
      for (int mf = 0; mf < 4; ++mf)
#pragma unroll
        for (int nf = 0; nf < 4; ++nf)
          acc[mf][nf] = __builtin_amdgcn_mfma_f32_16x16x32_bf16(af[mf], bfr[nf], acc[mf][nf], 0, 0, 0);
    }
    __syncthreads();
  }
#pragma unroll
  for (int mf = 0; mf < 4; ++mf)
#pragma unroll
    for (int nf = 0; nf < 4; ++nf) {
      int col = n0 + wc * 64 + nf * 16 + l15;
#pragma unroll
      for (int j = 0; j < 4; ++j) {
        int row = m0 + wr * 64 + mf * 16 + l4 * 4 + j;
        Cout[(size_t)row * Nn + col] = acc[mf][nf][j] + bias[col];
      }
    }
}

// ---------------------------------------------------------------- attention
// Swapped-QK^T 32x32 structure, KVBLK=128: 1 block = (b,h) x 128 q-rows,
// 4 waves x 32 q. S^T = mfma32(K, Q); softmax in-lane + 1 shfl; defer-rescale
// (THR=8); P->B-frag via cvt_pk + permlane32_swap. O^T += mfma32(V^T, P^T).
// launch_bounds (256,2): LDS caps at 2 blocks/CU; full VGPR budget.
__global__ __launch_bounds__(256, 2) void attn_kern(
    const unsigned short* __restrict__ Q,   // [B*H][2048][64]  (pre-scaled)
    const unsigned short* __restrict__ Kk,  // [B*H][2048][64]
    const unsigned short* __restrict__ Vt,  // [B*H][64][2048]
    unsigned short* __restrict__ O)         // [B][2048][1024]
{
  __shared__ unsigned short k_sh[2][128 * 64];
  __shared__ unsigned short v_sh[2][64 * 128];
  const int tid = threadIdx.x;
  const int lane = tid & 63;
  const int w = tid >> 6;
  const int l31 = lane & 31;
  const int H = lane >> 5;
  const int bid = blockIdx.x;
  const int wid = (bid & 7) * 64 + (bid >> 3);  // XCD swizzle: 4 bh per XCD
  const int qt = wid & 15;
  const int bh = wid >> 4;
  const int h = bh & 15, b = bh >> 4;
  const unsigned short* qb = Q + (size_t)bh * 2048 * 64;
  const unsigned short* kb = Kk + (size_t)bh * 2048 * 64;
  const unsigned short* vb = Vt + (size_t)bh * 64 * 2048;
  const int tok = qt * 128 + w * 32 + l31;

  // Q B-frags: lane holds Q[tok][c*16 + H*8 .. +7]
  bf16x8 qf[4];
#pragma unroll
  for (int c = 0; c < 4; ++c)
    qf[c] = *reinterpret_cast<const bf16x8*>(&qb[(size_t)tok * 64 + c * 16 + H * 8]);

  f32x16 oT[2] = {};
  float mr = -1e30f, lr = 0.f;

  const int r8 = lane >> 3, cc8 = lane & 7;    // K staging
  const int r4 = lane >> 4, cc16 = lane & 15;  // V staging
  // stage one 128-key tile: K 16 segs (8 rows x 128B), V^T 16 segs (4 rows x 256B)
#define ATTN_STAGE(KT, BUF)                                                           \
  {                                                                                   \
    _Pragma("unroll") for (int p = 0; p < 8; ++p) {                                   \
      int sseg = p * 4 + w;                                                           \
      if (sseg < 16) {                                                                \
        int row = sseg * 8 + r8;                                                      \
        async_copy16(&k_sh[BUF][sseg * 512],                                          \
                     &kb[(size_t)((KT) * 128 + row) * 64 + ((cc8 ^ (row & 7)) << 3)]);   \
      } else {                                                                        \
        int s2 = sseg - 16;                                                           \
        int row = s2 * 4 + r4;                                                        \
        async_copy16(&v_sh[BUF][s2 * 512],                                            \
                     &vb[(size_t)row * 2048 + (KT) * 128 + ((cc16 ^ (row & 7)) << 3)]);  \
      }                                                                               \
    }                                                                                 \
  }

  ATTN_STAGE(0, 0);
  __syncthreads();

  for (int kt = 0; kt < 16; ++kt) {
    const int cur = kt & 1;
    if (kt < 15) ATTN_STAGE(kt + 1, cur ^ 1);

    // S^T[k][q] for k-blocks t: 0..3, accumulate over d (4 chunks of 16)
    f32x16 sT[4] = {};
    __builtin_amdgcn_s_setprio(1);
#pragma unroll
    for (int c = 0; c < 4; ++c) {
      int ch0 = 2 * c + H;
#pragma unroll
      for (int t = 0; t < 4; ++t) {
        int r = t * 32 + l31;
        bf16x8 ka = *reinterpret_cast<const bf16x8*>(
            &k_sh[cur][r * 64 + (((ch0) ^ (r & 7)) << 3)]);
        sT[t] = __builtin_amdgcn_mfma_f32_32x32x16_bf16(ka, qf[c], sT[t], 0, 0, 0);
      }
    }
    __builtin_amdgcn_s_setprio(0);
    // online softmax for q = lane&31 (exp2 domain); defer-rescale THR=8
    float tmax = fmaxf(fmaxf(vmax16(sT[0]), vmax16(sT[1])),
                       fmaxf(vmax16(sT[2]), vmax16(sT[3])));
    tmax = fmaxf(tmax, __shfl_xor(tmax, 32));
    if (__any(tmax > mr + 8.f)) {
      float mn = fmaxf(mr, tmax);
      float corr = fast_exp2(mr - mn);
      mr = mn;
      lr *= corr;
#pragma unroll
      for (int r = 0; r < 16; ++r) { oT[0][r] *= corr; oT[1][r] *= corr; }
    }
    float tsum = 0.f;
#pragma unroll
    for (int t = 0; t < 4; ++t)
#pragma unroll
      for (int r = 0; r < 16; ++r) {
        float p = fast_exp2(sT[t][r] - mr);
        sT[t][r] = p;
        tsum += p;
      }
    tsum += __shfl_xor(tsum, 32);
    lr += tsum;

    // P^T -> B-operand frags (in-register): pB[2t+half] covers k=16(2t+half)..+15
    bf16x8 pB[8];
#pragma unroll
    for (int t = 0; t < 4; ++t)
#pragma unroll
      for (int half = 0; half < 2; ++half) {
        const int base = 8 * half;
        unsigned x0 = cvt_pk_bf16(sT[t][base + 0], sT[t][base + 1]);
        unsigned x1 = cvt_pk_bf16(sT[t][base + 2], sT[t][base + 3]);
        unsigned y0 = cvt_pk_bf16(sT[t][base + 4], sT[t][base + 5]);
        unsigned y1 = cvt_pk_bf16(sT[t][base + 6], sT[t][base + 7]);
        swap32(x0, y0);
        swap32(x1, y1);
        int4 packed = {(int)x0, (int)x1, (int)y0, (int)y1};
        pB[2 * t + half] = __builtin_bit_cast(bf16x8, packed);
      }
    // O^T += V^T * P^T
    __builtin_amdgcn_s_setprio(1);
#pragma unroll
    for (int dt = 0; dt < 2; ++dt) {
      int r = dt * 32 + l31;
#pragma unroll
      for (int mi = 0; mi < 8; ++mi) {
        int ch = (mi * 2 + H) ^ (r & 7);
        bf16x8 va = *reinterpret_cast<const bf16x8*>(&v_sh[cur][r * 128 + (ch << 3)]);
        oT[dt] = __builtin_amdgcn_mfma_f32_32x32x16_bf16(va, pB[mi], oT[dt], 0, 0, 0);
      }
    }
    __builtin_amdgcn_s_setprio(0);
    __syncthreads();
  }
  // epilogue: O[b, tok, h*64 + d], d = (reg&3) + 8*(reg>>2) + 4*H + 32*dt
  float invl = 1.f / lr;
#pragma unroll
  for (int dt = 0; dt < 2; ++dt)
#pragma unroll
    for (int rb = 0; rb < 4; ++rb) {
      us4 ov;
#pragma unroll
      for (int j = 0; j < 4; ++j) ov[j] = f2b(oT[dt][rb * 4 + j] * invl);
      *reinterpret_cast<us4*>(
          &O[((size_t)b * 2048 + tok) * 1024 + h * 64 + 32 * dt + 8 * rb + 4 * H]) = ov;
    }
#undef ATTN_STAGE
}

// ---------------------------------------------------------------- launch
extern "C" void kernel_launch(void* const* d_in, const int* in_sizes, int n_in,
                              void* d_out, int out_size, void* d_ws, size_t ws_size,
                              hipStream_t stream) {
  (void)in_sizes; (void)n_in; (void)out_size; (void)ws_size;
  const float* x      = (const float*)d_in[0];
  const float* w_qkv  = (const float*)d_in[1];
  const float* w_proj = (const float*)d_in[2];
  const float* b_proj = (const float*)d_in[3];
  const float* fcos   = (const float*)d_in[4];
  const float* fsin   = (const float*)d_in[5];
  float* out = (float*)d_out;
  char* ws = (char*)d_ws;

  unsigned short* x_bf     = (unsigned short*)(ws + 0);         // 8 MB
  unsigned short* wqkv_bf  = (unsigned short*)(ws + 8388608);   // 6 MB
  unsigned short* wproj_bf = (unsigned short*)(ws + 14680064);  // 2 MB
  unsigned short* q_bf     = (unsigned short*)(ws + 16777216);  // 8 MB
  unsigned short* k_bf     = (unsigned short*)(ws + 25165824);  // 8 MB
  unsigned short* vt_bf    = (unsigned short*)(ws + 33554432);  // 8 MB
  unsigned short* ao_bf    = (unsigned short*)(ws + 41943040);  // 8 MB (total 48 MB)

  cvt_bf16<<<2048, 256, 0, stream>>>(x, x_bf, 4096 * 1024 / 8);
  cvt_bf16<<<1536, 256, 0, stream>>>(w_qkv, wqkv_bf, 3072 * 1024 / 8);
  cvt_bf16<<<512, 256, 0, stream>>>(w_proj, wproj_bf, 1024 * 1024 / 8);
  gemm_qkv<<<dim3(24, 32), 256, 0, stream>>>(x_bf, wqkv_bf, fcos, fsin,
                                             q_bf, k_bf, vt_bf);
  attn_kern<<<512, 256, 0, stream>>>(q_bf, k_bf, vt_bf, ao_bf);
  gemm_proj<<<dim3(8, 32), 256, 0, stream>>>(ao_bf, wproj_bf, b_proj, out,
                                             4096, 1024, 1024);
}